// Round 11
// baseline (3688.105 us; speedup 1.0000x reference)
//
#include <hip/hip_runtime.h>
#include <math.h>

#define H 256
#define H4 1024
#define Bsz 1024
#define TIN 168
#define TOUT 24
#define Fh 8
#define XROW (TIN*Fh)
#define BH ((size_t)Bsz * H)          // 262144
#define SL64 ((size_t)Bsz * 64)       // elems per 64-unit slice block of swizzled h

typedef __attribute__((ext_vector_type(8))) short bf16x8;
typedef __attribute__((ext_vector_type(4))) float f32x4;

__device__ __forceinline__ ushort f2bf(float f) {
    union { float f; unsigned u; } v; v.f = f;
    unsigned r = v.u + 0x7fff + ((v.u >> 16) & 1);
    return (ushort)(r >> 16);
}
__device__ __forceinline__ float bf2f(ushort u) {
    union { unsigned u; float f; } v; v.u = ((unsigned)u) << 16;
    return v.f;
}
__device__ __forceinline__ float sigmf(float x) {
    return __fdividef(1.0f, 1.0f + __expf(-x));
}
__device__ __forceinline__ float tanhf_(float x) {
    const float e = __expf(-2.0f * fabsf(x));
    const float t = __fdividef(1.0f - e, 1.0f + e);
    return copysignf(t, x);
}

// ---- sc0sc1 (MALL, cross-XCD coherent) ----
__device__ __forceinline__ void load_coh4f(const float* p0, const float* p1,
                                           const float* p2, const float* p3,
                                           float& a, float& b, float& c, float& d)
{
    asm volatile(
        "global_load_dword %0, %4, off sc0 sc1\n\t"
        "global_load_dword %1, %5, off sc0 sc1\n\t"
        "global_load_dword %2, %6, off sc0 sc1\n\t"
        "global_load_dword %3, %7, off sc0 sc1\n\t"
        "s_waitcnt vmcnt(0)"
        : "=&v"(a), "=&v"(b), "=&v"(c), "=&v"(d)
        : "v"(p0), "v"(p1), "v"(p2), "v"(p3)
        : "memory");
}
__device__ __forceinline__ void load_coh16Bx(const ushort* p, f32x4& v) {
    asm volatile("global_load_dwordx4 %0, %1, off sc0 sc1\n\ts_waitcnt vmcnt(0)"
                 : "=&v"(v) : "v"(p) : "memory");
}
__device__ __forceinline__ void store_coh8B(ushort* p, uint2 v) {
    asm volatile("global_store_dwordx2 %0, %1, off sc0 sc1"
                 :: "v"(p), "v"(v) : "memory");
}
__device__ __forceinline__ void store_coh16B(float* p, f32x4 v) {
    asm volatile("global_store_dwordx4 %0, %1, off sc0 sc1"
                 :: "v"(p), "v"(v) : "memory");
}

// ---- sc0-only (XCD-local L2; producer+consumer share the XCD) ----
__device__ __forceinline__ void load_l2_4(const ushort* p0, const ushort* p1,
                                          const ushort* p2, const ushort* p3,
                                          f32x4& a, f32x4& b, f32x4& c, f32x4& d)
{
    asm volatile(
        "global_load_dwordx4 %0, %4, off sc0\n\t"
        "global_load_dwordx4 %1, %5, off sc0\n\t"
        "global_load_dwordx4 %2, %6, off sc0\n\t"
        "global_load_dwordx4 %3, %7, off sc0\n\t"
        "s_waitcnt vmcnt(0)"
        : "=&v"(a), "=&v"(b), "=&v"(c), "=&v"(d)
        : "v"(p0), "v"(p1), "v"(p2), "v"(p3)
        : "memory");
}
__device__ __forceinline__ void store_l2_8B(ushort* p, uint2 v) {
    asm volatile("global_store_dwordx2 %0, %1, off sc0"
                 :: "v"(p), "v"(v) : "memory");
}

// MALL barrier — R6/R9-proven relaxed-atomic scheme (no L2 invalidation,
// cheap polls). Used for ALL barriers; data coherence comes from the memory
// ops' own scope (sc0 within an XCD, sc0sc1 across).
__device__ __forceinline__ void gbar(unsigned* cnt, unsigned target) {
    asm volatile("s_waitcnt vmcnt(0)" ::: "memory");
    __syncthreads();
    if (threadIdx.x == 0) {
        __hip_atomic_fetch_add(cnt, 1u, __ATOMIC_RELAXED, __HIP_MEMORY_SCOPE_AGENT);
        int sp = 0;
        while (__hip_atomic_fetch_add(cnt, 0u, __ATOMIC_RELAXED,
                                      __HIP_MEMORY_SCOPE_AGENT) < target) {
            __builtin_amdgcn_s_sleep(2);
            if (++sp > 20000) break;   // failsafe: fails absmax, never hangs
        }
    }
    __syncthreads();
    asm volatile("" ::: "memory");
}

__global__ __launch_bounds__(256)
void cast_f32_bf16(const float* __restrict__ in, ushort* __restrict__ out, int n) {
    int i = blockIdx.x * 256 + threadIdx.x;
    const int stride = gridDim.x * 256;
    for (; i < n; i += stride) out[i] = f2bf(in[i]);
}

__global__ __launch_bounds__(256)
void cast_pad_wih0(const float* __restrict__ in, ushort* __restrict__ out) {
    const int idx = blockIdx.x * 256 + threadIdx.x;
    const int row = idx >> 5, c = idx & 31;
    out[idx] = (c < 8) ? f2bf(in[row * 8 + c]) : (ushort)0;
}

__global__ __launch_bounds__(256)
void precompute_kernel(const float* __restrict__ oW, const float* __restrict__ ob,
                       const float* __restrict__ f2W, const float* __restrict__ f2b,
                       const float* __restrict__ inW, const float* __restrict__ inb,
                       float* __restrict__ u, float* __restrict__ dconst,
                       float* __restrict__ ccv)
{
    __shared__ float wsh[256];
    const int f = blockIdx.x;
    const int tid = threadIdx.x;
    float s = 0.f;
    for (int i = 0; i < 256; ++i)
        s += f2W[f * 256 + i] * oW[(size_t)f * 65536 + (size_t)i * 256 + tid];
    wsh[tid] = s;
    __syncthreads();
    float su = 0.f;
    for (int n = 0; n < 256; ++n)
        su += wsh[n] * inW[(size_t)f * 768 * 256 + (size_t)(512 + n) * 256 + tid];
    u[f * 256 + tid] = su;
    if (tid == 0) {
        float dd = 0.f, cc = 0.f;
        for (int n = 0; n < 256; ++n) dd += wsh[n] * inb[f * 768 + 512 + n];
        for (int i = 0; i < 256; ++i) cc += ob[f * 256 + i] * f2W[f * 256 + i];
        dconst[f] = dd;
        ccv[f] = cc + f2b[f];
    }
}

struct MP {
    const float *x, *ebih0, *ebhh0, *ebih1, *ebhh1;
    const ushort *Whh0, *Wih0p, *Wih1, *Whh1;
    ushort *h0A, *h0B, *h1A, *h1B, *hm;
    float *cm;
    const ushort *dWhh, *f1Wb, *inWb;
    const float *dWih, *dbih, *dbhh, *f1b, *inb, *u, *dconst, *ccv;
    ushort *kb0, *kb1;
    float *vw0, *vw1, *out;
    unsigned *bar;
};

// ---------------------------------------------------------------------------
// One persistent kernel. Hybrid of R9 (MALL relaxed barriers — proven cheap)
// and R10 (same-XCD group geometry + sc0 L2-local h-exchange — proven 30x
// traffic cut).
// ENCODER: 64 groups x 4 WGs, all members same XCD (grp=bid&63, slice=bid>>6).
// DECODER: f pinned to XCD=bid&7; h in LDS, c in regs; k/vw via XCD L2 sc0.
// ---------------------------------------------------------------------------
__global__ __launch_bounds__(256, 1)
void mega5(MP P)
{
    __shared__ __align__(16) ushort SA[16][264];
    __shared__ __align__(16) ushort SC[16][264];
    __shared__ __align__(16) float pre0[4][16][68];
    __shared__ __align__(16) float pre1[4][16][68];
    __shared__ __align__(16) ushort xL[16][32];
    __shared__ __align__(16) ushort h2s[32][264];
    __shared__ __align__(16) ushort as2[32][264];
    __shared__ __align__(16) ushort qs[32][264];
    __shared__ float tri[4][2][16][3];
    __shared__ float dinL[32];

    const int bid = blockIdx.x;
    const int tid = threadIdx.x;
    const int l = tid & 63, w = tid >> 6;
    const int lr = l & 15, lq = l >> 4, lk = lq * 8;

    // ======================= ENCODER (same-XCD groups) =======================
    {
        const int wgi = bid >> 6;          // 0..3: 64-unit slice
        const int grp = bid & 63;          // 0..63: row group; XCD = grp%8
        const int rowbase = grp * 16;
        const int ub = wgi * 64;
        unsigned* cnt = P.bar + grp * 32;
        const int g = w;                   // wave = gate

        for (int e = tid; e < 16 * 32; e += 256) (&xL[0][0])[e] = 0;

        const int crow = tid >> 4;         // 0..15
        const int cu = (tid & 15) * 4;     // 0..60
        float c0v[4] = {0,0,0,0}, c1v[4] = {0,0,0,0};
        float h0v[4] = {0,0,0,0}, h1v[4] = {0,0,0,0};

        float b0s[4], b1s[4];
#pragma unroll
        for (int n = 0; n < 4; ++n) {
            const int j = ub + n * 16 + lr;
            b0s[n] = P.ebih0[g * H + j] + P.ebhh0[g * H + j];
            b1s[n] = P.ebih1[g * H + j] + P.ebhh1[g * H + j];
        }
        // staging chunk geometry: thread t owns chunks t and t+256
        const int r1 = tid >> 5, c8 = tid & 31;
        const int gcol = ((c8 >> 3) << 6) | ((c8 & 7) << 3);
        const size_t off1 = (size_t)(c8 >> 3) * SL64 + (size_t)(rowbase + r1) * 64 + (c8 & 7) * 8;
        const size_t off2 = off1 + 8 * 64;   // r2 = r1 + 8

        unsigned bph = 0;
        __syncthreads();

        for (int i = 0; i <= TIN; ++i) {
            ushort*       h0wb = (i & 1) ? P.h0B : P.h0A;
            const ushort* h0rb = (i & 1) ? P.h0A : P.h0B;
            ushort*       h1wb = (i & 1) ? P.h1A : P.h1B;
            const ushort* h1rb = (i & 1) ? P.h1B : P.h1A;

            {   // stage SA <- h0[i-1], SC <- h1[i-2] from XCD-local L2
                f32x4 v0, v1, v2, v3;
                load_l2_4(h0rb + off1, h0rb + off2, h1rb + off1, h1rb + off2,
                          v0, v1, v2, v3);
                *(f32x4*)&SA[r1][gcol] = v0;
                *(f32x4*)&SA[r1 + 8][gcol] = v1;
                *(f32x4*)&SC[r1][gcol] = v2;
                *(f32x4*)&SC[r1 + 8][gcol] = v3;
                if (i < TIN && tid < 128)
                    xL[tid >> 3][tid & 7] =
                        f2bf(P.x[(size_t)(rowbase + (tid >> 3)) * XROW + i * Fh + (tid & 7)]);
            }
            __syncthreads();

            bf16x8 aS[8], aC[8], ax;
#pragma unroll
            for (int k = 0; k < 8; ++k) {
                aS[k] = *(const bf16x8*)&SA[lr][k * 32 + lk];
                aC[k] = *(const bf16x8*)&SC[lr][k * 32 + lk];
            }
            ax = *(const bf16x8*)&xL[lr][lk];

            if (i < TIN) {  // L0(i): gate g = h0[i-1]@Whh0^T + x(i)@Wih0p^T
                f32x4 acc[4] = {};
#pragma unroll
                for (int n = 0; n < 4; ++n) {
                    const ushort* wp = P.Whh0 + (size_t)(g * H + ub + n * 16 + lr) * H + lk;
#pragma unroll
                    for (int k = 0; k < 8; ++k) {
                        const bf16x8 b8 = *(const bf16x8*)(wp + k * 32);
                        acc[n] = __builtin_amdgcn_mfma_f32_16x16x32_bf16(aS[k], b8, acc[n], 0, 0, 0);
                    }
                    const bf16x8 bx = *(const bf16x8*)(P.Wih0p + (size_t)(g * H + ub + n * 16 + lr) * 32 + lk);
                    acc[n] = __builtin_amdgcn_mfma_f32_16x16x32_bf16(ax, bx, acc[n], 0, 0, 0);
                }
#pragma unroll
                for (int n = 0; n < 4; ++n)
#pragma unroll
                    for (int r = 0; r < 4; ++r)
                        pre0[g][lq * 4 + r][n * 16 + lr] = acc[n][r] + b0s[n];
            }
            if (i >= 1) {   // L1(i-1): gate g = h0[i-1]@Wih1^T + h1[i-2]@Whh1^T
                f32x4 acc[4] = {};
#pragma unroll
                for (int n = 0; n < 4; ++n) {
                    const ushort* w1 = P.Wih1 + (size_t)(g * H + ub + n * 16 + lr) * H + lk;
                    const ushort* w2 = P.Whh1 + (size_t)(g * H + ub + n * 16 + lr) * H + lk;
#pragma unroll
                    for (int k = 0; k < 8; ++k) {
                        const bf16x8 b1 = *(const bf16x8*)(w1 + k * 32);
                        acc[n] = __builtin_amdgcn_mfma_f32_16x16x32_bf16(aS[k], b1, acc[n], 0, 0, 0);
                        const bf16x8 b2 = *(const bf16x8*)(w2 + k * 32);
                        acc[n] = __builtin_amdgcn_mfma_f32_16x16x32_bf16(aC[k], b2, acc[n], 0, 0, 0);
                    }
                }
#pragma unroll
                for (int n = 0; n < 4; ++n)
#pragma unroll
                    for (int r = 0; r < 4; ++r)
                        pre1[g][lq * 4 + r][n * 16 + lr] = acc[n][r] + b1s[n];
            }
            __syncthreads();

            if (i < TIN) {
                const f32x4 pi = *(const f32x4*)&pre0[0][crow][cu];
                const f32x4 pf = *(const f32x4*)&pre0[1][crow][cu];
                const f32x4 pg = *(const f32x4*)&pre0[2][crow][cu];
                const f32x4 po = *(const f32x4*)&pre0[3][crow][cu];
#pragma unroll
                for (int j = 0; j < 4; ++j) {
                    const float ig = sigmf(pi[j]);
                    const float fg = sigmf(pf[j]);
                    const float gg = tanhf_(pg[j]);
                    const float og = sigmf(po[j]);
                    c0v[j] = fg * c0v[j] + ig * gg;
                    h0v[j] = og * tanhf_(c0v[j]);
                }
                uint2 hp;
                hp.x = (unsigned)f2bf(h0v[0]) | ((unsigned)f2bf(h0v[1]) << 16);
                hp.y = (unsigned)f2bf(h0v[2]) | ((unsigned)f2bf(h0v[3]) << 16);
                store_l2_8B(h0wb + (size_t)wgi * SL64 + (size_t)(rowbase + crow) * 64 + cu, hp);
            }
            if (i >= 1) {
                const f32x4 pi = *(const f32x4*)&pre1[0][crow][cu];
                const f32x4 pf = *(const f32x4*)&pre1[1][crow][cu];
                const f32x4 pg = *(const f32x4*)&pre1[2][crow][cu];
                const f32x4 po = *(const f32x4*)&pre1[3][crow][cu];
#pragma unroll
                for (int j = 0; j < 4; ++j) {
                    const float ig = sigmf(pi[j]);
                    const float fg = sigmf(pf[j]);
                    const float gg = tanhf_(pg[j]);
                    const float og = sigmf(po[j]);
                    c1v[j] = fg * c1v[j] + ig * gg;
                    h1v[j] = og * tanhf_(c1v[j]);
                }
                uint2 hp;
                hp.x = (unsigned)f2bf(h1v[0]) | ((unsigned)f2bf(h1v[1]) << 16);
                hp.y = (unsigned)f2bf(h1v[2]) | ((unsigned)f2bf(h1v[3]) << 16);
                store_l2_8B(h1wb + (size_t)wgi * SL64 + (size_t)(rowbase + crow) * 64 + cu, hp);
            }
            gbar(cnt, ++bph * 4u);
        }
        // tail: hm/cm (MALL; consumed cross-XCD by decoder)
        {
            uint2 hp;
            hp.x = (unsigned)f2bf(0.5f * (h0v[0] + h1v[0]))
                 | ((unsigned)f2bf(0.5f * (h0v[1] + h1v[1])) << 16);
            hp.y = (unsigned)f2bf(0.5f * (h0v[2] + h1v[2]))
                 | ((unsigned)f2bf(0.5f * (h0v[3] + h1v[3])) << 16);
            store_coh8B(P.hm + (size_t)(rowbase + crow) * 256 + ub + cu, hp);
            f32x4 cv;
#pragma unroll
            for (int j = 0; j < 4; ++j) cv[j] = 0.5f * (c0v[j] + c1v[j]);
            store_coh16B(P.cm + (size_t)(rowbase + crow) * 256 + ub + cu, cv);
        }
    }
    gbar(P.bar + 2560, 256u);   // cross-XCD grid barrier (MALL)

    // ======================= DECODER =======================
    {
        const int f = bid & 7, mb = bid >> 3;  // XCD = bid%8 = f
        const int m0 = mb * 32;

#pragma unroll
        for (int it = 0; it < 4; ++it) {
            const int idx = tid + it * 256;
            const int r = idx >> 5, c16 = (idx & 31) * 8;
            f32x4 v0;
            load_coh16Bx(P.hm + (size_t)(m0 + r) * 256 + c16, v0);
            *(f32x4*)&h2s[r][c16] = v0;
        }
        float cd[2][4][4];
#pragma unroll
        for (int m = 0; m < 2; ++m)
#pragma unroll
            for (int jt = 0; jt < 4; ++jt) {
                const float* pc = P.cm + (size_t)(m0 + m * 16 + lq * 4) * 256
                                + (w * 64 + jt * 16 + lr);
                load_coh4f(pc, pc + 256, pc + 512, pc + 768,
                           cd[m][jt][0], cd[m][jt][1], cd[m][jt][2], cd[m][jt][3]);
            }
        float bsum[4][4], wxr[4][4];
#pragma unroll
        for (int jt = 0; jt < 4; ++jt)
#pragma unroll
            for (int g = 0; g < 4; ++g) {
                const int j = w * 64 + jt * 16 + lr;
                bsum[jt][g] = P.dbih[f * H4 + g * H + j] + P.dbhh[f * H4 + g * H + j];
                wxr[jt][g] = P.dWih[f * H4 + g * H + j];
            }
        __syncthreads();

        unsigned* fcnt = P.bar + 2048 + f * 32;

        for (int t = 0; t < TOUT; ++t) {
            ushort* kcur = (t & 1) ? P.kb1 : P.kb0;
            float* vwcur = (t & 1) ? P.vw1 : P.vw0;

            float xiv[2][4];
#pragma unroll
            for (int m = 0; m < 2; ++m)
#pragma unroll
                for (int r = 0; r < 4; ++r) {
                    const int row = m * 16 + lq * 4 + r;
                    xiv[m][r] = (t == 0)
                        ? P.x[(size_t)(m0 + row) * XROW + (TIN - 1) * Fh + f]
                        : dinL[row];
                }
            bf16x8 af[2][8];
#pragma unroll
            for (int m = 0; m < 2; ++m)
#pragma unroll
                for (int k = 0; k < 8; ++k)
                    af[m][k] = *(const bf16x8*)&h2s[m * 16 + lr][k * 32 + lk];
            __syncthreads();
            const ushort* Wb = P.dWhh + (size_t)f * (H4 * H);
#pragma unroll 1
            for (int jt = 0; jt < 4; ++jt) {
                const int j = w * 64 + jt * 16 + lr;
                f32x4 acc[4][2] = {};
#pragma unroll
                for (int g = 0; g < 4; ++g) {
                    const ushort* wp = Wb + (size_t)(g * H + j) * H + lk;
#pragma unroll
                    for (int k = 0; k < 8; ++k) {
                        const bf16x8 b8 = *(const bf16x8*)(wp + k * 32);
                        acc[g][0] = __builtin_amdgcn_mfma_f32_16x16x32_bf16(af[0][k], b8, acc[g][0], 0, 0, 0);
                        acc[g][1] = __builtin_amdgcn_mfma_f32_16x16x32_bf16(af[1][k], b8, acc[g][1], 0, 0, 0);
                    }
                }
#pragma unroll
                for (int m = 0; m < 2; ++m)
#pragma unroll
                    for (int r = 0; r < 4; ++r) {
                        const int row = m * 16 + lq * 4 + r;
                        const float xi = xiv[m][r];
                        const float ig = sigmf(acc[0][m][r] + bsum[jt][0] + xi * wxr[jt][0]);
                        const float fg = sigmf(acc[1][m][r] + bsum[jt][1] + xi * wxr[jt][1]);
                        const float gg = tanhf_(acc[2][m][r] + bsum[jt][2] + xi * wxr[jt][2]);
                        const float og = sigmf(acc[3][m][r] + bsum[jt][3] + xi * wxr[jt][3]);
                        const float cn = fg * cd[m][jt][r] + ig * gg;
                        cd[m][jt][r] = cn;
                        h2s[row][j] = f2bf(og * tanhf_(cn));
                    }
            }
            __syncthreads();
            bf16x8 a2[2][8];
#pragma unroll
            for (int m = 0; m < 2; ++m)
#pragma unroll
                for (int k = 0; k < 8; ++k)
                    a2[m][k] = *(const bf16x8*)&h2s[m * 16 + lr][k * 32 + lk];
            const ushort* Wf = P.f1Wb + (size_t)f * H * H;
#pragma unroll 1
            for (int nt = 0; nt < 4; ++nt) {
                const int n = w * 64 + nt * 16 + lr;
                f32x4 acc0 = {}, acc1 = {};
                const ushort* wp = Wf + (size_t)n * H + lk;
#pragma unroll
                for (int k = 0; k < 8; ++k) {
                    const bf16x8 b8 = *(const bf16x8*)(wp + k * 32);
                    acc0 = __builtin_amdgcn_mfma_f32_16x16x32_bf16(a2[0][k], b8, acc0, 0, 0, 0);
                    acc1 = __builtin_amdgcn_mfma_f32_16x16x32_bf16(a2[1][k], b8, acc1, 0, 0, 0);
                }
                const float bv = P.f1b[f * H + n];
#pragma unroll
                for (int r = 0; r < 4; ++r) {
                    float v0 = acc0[r] + bv; v0 = (v0 > 0.f) ? v0 : 0.01f * v0;
                    as2[lq * 4 + r][n] = f2bf(v0);
                    float v1 = acc1[r] + bv; v1 = (v1 > 0.f) ? v1 : 0.01f * v1;
                    as2[16 + lq * 4 + r][n] = f2bf(v1);
                }
            }
            __syncthreads();
            bf16x8 a3[2][8];
#pragma unroll
            for (int m = 0; m < 2; ++m)
#pragma unroll
                for (int k = 0; k < 8; ++k)
                    a3[m][k] = *(const bf16x8*)&as2[m * 16 + lr][k * 32 + lk];
            const ushort* Wi = P.inWb + (size_t)f * 768 * H;
#pragma unroll 1
            for (int nt = 0; nt < 8; ++nt) {
                const int n0 = w * 128 + nt * 16;
                f32x4 acc0 = {}, acc1 = {};
                const ushort* wp = Wi + (size_t)(n0 + lr) * H + lk;
#pragma unroll
                for (int k = 0; k < 8; ++k) {
                    const bf16x8 b8 = *(const bf16x8*)(wp + k * 32);
                    acc0 = __builtin_amdgcn_mfma_f32_16x16x32_bf16(a3[0][k], b8, acc0, 0, 0, 0);
                    acc1 = __builtin_amdgcn_mfma_f32_16x16x32_bf16(a3[1][k], b8, acc1, 0, 0, 0);
                }
                const float bv = P.inb[f * 768 + n0 + lr];
#pragma unroll
                for (int m = 0; m < 2; ++m)
#pragma unroll
                    for (int r = 0; r < 4; ++r) {
                        const float v = (m ? acc1[r] : acc0[r]) + bv;
                        const int row = m * 16 + lq * 4 + r;
                        if (n0 < 256)
                            qs[row][n0 + lr] = f2bf(v * 0.0625f);
                        else
                            kcur[((size_t)f * Bsz + m0 + row) * H + n0 - 256 + lr] = f2bf(v);
                    }
            }
            {
                const float4 u4 = *(const float4*)(P.u + f * H + l * 4);
#pragma unroll 1
                for (int rr = 0; rr < 8; ++rr) {
                    const int mloc = w * 8 + rr;
                    const ushort4 a4 = *(const ushort4*)&as2[mloc][l * 4];
                    float s = bf2f(a4.x) * u4.x + bf2f(a4.y) * u4.y
                            + bf2f(a4.z) * u4.z + bf2f(a4.w) * u4.w;
#pragma unroll
                    for (int d = 1; d < 64; d <<= 1) s += __shfl_xor(s, d);
                    if (l == 0) vwcur[f * Bsz + m0 + mloc] = s + P.dconst[f];
                }
            }
            gbar(fcnt, (unsigned)(t + 1) * 32u);
            {
                bf16x8 qf[2][8];
#pragma unroll
                for (int m = 0; m < 2; ++m)
#pragma unroll
                    for (int k = 0; k < 8; ++k)
                        qf[m][k] = *(const bf16x8*)&qs[m * 16 + lr][k * 32 + lk];
                float mM0 = -1e30f, lS0 = 0.f, oS0 = 0.f;
                float mM1 = -1e30f, lS1 = 0.f, oS1 = 0.f;
                const int kb0r = w * 256;
#pragma unroll 1
                for (int kf = 0; kf < 16; kf += 2) {
                    const int kbA = kb0r + kf * 16;
                    const ushort* baseA = kcur + ((size_t)f * Bsz + kbA + lr) * H + lk;
                    const ushort* baseB = baseA + 16 * H;
                    const float* pvA = vwcur + f * Bsz + kbA + lq * 4;
                    const float* pvB = pvA + 16;
                    f32x4 A0, A1, A2, A3, A4, A5, A6, A7;
                    f32x4 B0, B1, B2, B3, B4, B5, B6, B7;
                    f32x4 vA, vB;
                    asm volatile(
                        "global_load_dwordx4 %0, %18, off sc0\n\t"
                        "global_load_dwordx4 %1, %18, off offset:64 sc0\n\t"
                        "global_load_dwordx4 %2, %18, off offset:128 sc0\n\t"
                        "global_load_dwordx4 %3, %18, off offset:192 sc0\n\t"
                        "global_load_dwordx4 %4, %18, off offset:256 sc0\n\t"
                        "global_load_dwordx4 %5, %18, off offset:320 sc0\n\t"
                        "global_load_dwordx4 %6, %18, off offset:384 sc0\n\t"
                        "global_load_dwordx4 %7, %18, off offset:448 sc0\n\t"
                        "global_load_dwordx4 %8, %19, off sc0\n\t"
                        "global_load_dwordx4 %9, %19, off offset:64 sc0\n\t"
                        "global_load_dwordx4 %10, %19, off offset:128 sc0\n\t"
                        "global_load_dwordx4 %11, %19, off offset:192 sc0\n\t"
                        "global_load_dwordx4 %12, %19, off offset:256 sc0\n\t"
                        "global_load_dwordx4 %13, %19, off offset:320 sc0\n\t"
                        "global_load_dwordx4 %14, %19, off offset:384 sc0\n\t"
                        "global_load_dwordx4 %15, %19, off offset:448 sc0\n\t"
                        "global_load_dwordx4 %16, %20, off sc0\n\t"
                        "global_load_dwordx4 %17, %21, off sc0\n\t"
                        "s_waitcnt vmcnt(0)"
                        : "=&v"(A0), "=&v"(A1), "=&v"(A2), "=&v"(A3),
                          "=&v"(A4), "=&v"(A5), "=&v"(A6), "=&v"(A7),
                          "=&v"(B0), "=&v"(B1), "=&v"(B2), "=&v"(B3),
                          "=&v"(B4), "=&v"(B5), "=&v"(B6), "=&v"(B7),
                          "=&v"(vA), "=&v"(vB)
                        : "v"(baseA), "v"(baseB), "v"(pvA), "v"(pvB)
                        : "memory");
                    __builtin_amdgcn_sched_barrier(0);
                    {
                        f32x4 acc0 = {}, acc1 = {};
                        const bf16x8 k0 = *(bf16x8*)&A0, k1 = *(bf16x8*)&A1,
                                     k2 = *(bf16x8*)&A2, k3 = *(bf16x8*)&A3,
                                     k4 = *(bf16x8*)&A4, k5 = *(bf16x8*)&A5,
                                     k6 = *(bf16x8*)&A6, k7 = *(bf16x8*)&A7;
                        acc0 = __builtin_amdgcn_mfma_f32_16x16x32_bf16(k0, qf[0][0], acc0, 0, 0, 0);
                        acc1 = __builtin_amdgcn_mfma_f32_16x16x32_bf16(k0, qf[1][0], acc1, 0, 0, 0);
                        acc0 = __builtin_amdgcn_mfma_f32_16x16x32_bf16(k1, qf[0][1], acc0, 0, 0, 0);
                        acc1 = __builtin_amdgcn_mfma_f32_16x16x32_bf16(k1, qf[1][1], acc1, 0, 0, 0);
                        acc0 = __builtin_amdgcn_mfma_f32_16x16x32_bf16(k2, qf[0][2], acc0, 0, 0, 0);
                        acc1 = __builtin_amdgcn_mfma_f32_16x16x32_bf16(k2, qf[1][2], acc1, 0, 0, 0);
                        acc0 = __builtin_amdgcn_mfma_f32_16x16x32_bf16(k3, qf[0][3], acc0, 0, 0, 0);
                        acc1 = __builtin_amdgcn_mfma_f32_16x16x32_bf16(k3, qf[1][3], acc1, 0, 0, 0);
                        acc0 = __builtin_amdgcn_mfma_f32_16x16x32_bf16(k4, qf[0][4], acc0, 0, 0, 0);
                        acc1 = __builtin_amdgcn_mfma_f32_16x16x32_bf16(k4, qf[1][4], acc1, 0, 0, 0);
                        acc0 = __builtin_amdgcn_mfma_f32_16x16x32_bf16(k5, qf[0][5], acc0, 0, 0, 0);
                        acc1 = __builtin_amdgcn_mfma_f32_16x16x32_bf16(k5, qf[1][5], acc1, 0, 0, 0);
                        acc0 = __builtin_amdgcn_mfma_f32_16x16x32_bf16(k6, qf[0][6], acc0, 0, 0, 0);
                        acc1 = __builtin_amdgcn_mfma_f32_16x16x32_bf16(k6, qf[1][6], acc1, 0, 0, 0);
                        acc0 = __builtin_amdgcn_mfma_f32_16x16x32_bf16(k7, qf[0][7], acc0, 0, 0, 0);
                        acc1 = __builtin_amdgcn_mfma_f32_16x16x32_bf16(k7, qf[1][7], acc1, 0, 0, 0);
                        {
                            const float mx = fmaxf(fmaxf(acc0[0], acc0[1]), fmaxf(acc0[2], acc0[3]));
                            const float mn = fmaxf(mM0, mx);
                            const float sc = __expf(mM0 - mn);
                            const float e0 = __expf(acc0[0] - mn), e1 = __expf(acc0[1] - mn);
                            const float e2 = __expf(acc0[2] - mn), e3 = __expf(acc0[3] - mn);
                            lS0 = lS0 * sc + (e0 + e1 + e2 + e3);
                            oS0 = oS0 * sc + (e0 * vA[0] + e1 * vA[1] + e2 * vA[2] + e3 * vA[3]);
                            mM0 = mn;
                        }
                        {
                            const float mx = fmaxf(fmaxf(acc1[0], acc1[1]), fmaxf(acc1[2], acc1[3]));
                            const float mn = fmaxf(mM1, mx);
                            const float sc = __expf(mM1 - mn);
                            const float e0 = __expf(acc1[0] - mn), e1 = __expf(acc1[1] - mn);
                            const float e2 = __expf(acc1[2] - mn), e3 = __expf(acc1[3] - mn);
                            lS1 = lS1 * sc + (e0 + e1 + e2 + e3);
                            oS1 = oS1 * sc + (e0 * vA[0] + e1 * vA[1] + e2 * vA[2] + e3 * vA[3]);
                            mM1 = mn;
                        }
                    }
                    {
                        f32x4 acc0 = {}, acc1 = {};
                        const bf16x8 k0 = *(bf16x8*)&B0, k1 = *(bf16x8*)&B1,
                                     k2 = *(bf16x8*)&B2, k3 = *(bf16x8*)&B3,
                                     k4 = *(bf16x8*)&B4, k5 = *(bf16x8*)&B5,
                                     k6 = *(bf16x8*)&B6, k7 = *(bf16x8*)&B7;
                        acc0 = __builtin_amdgcn_mfma_f32_16x16x32_bf16(k0, qf[0][0], acc0, 0, 0, 0);
                        acc1 = __builtin_amdgcn_mfma_f32_16x16x32_bf16(k0, qf[1][0], acc1, 0, 0, 0);
                        acc0 = __builtin_amdgcn_mfma_f32_16x16x32_bf16(k1, qf[0][1], acc0, 0, 0, 0);
                        acc1 = __builtin_amdgcn_mfma_f32_16x16x32_bf16(k1, qf[1][1], acc1, 0, 0, 0);
                        acc0 = __builtin_amdgcn_mfma_f32_16x16x32_bf16(k2, qf[0][2], acc0, 0, 0, 0);
                        acc1 = __builtin_amdgcn_mfma_f32_16x16x32_bf16(k2, qf[1][2], acc1, 0, 0, 0);
                        acc0 = __builtin_amdgcn_mfma_f32_16x16x32_bf16(k3, qf[0][3], acc0, 0, 0, 0);
                        acc1 = __builtin_amdgcn_mfma_f32_16x16x32_bf16(k3, qf[1][3], acc1, 0, 0, 0);
                        acc0 = __builtin_amdgcn_mfma_f32_16x16x32_bf16(k4, qf[0][4], acc0, 0, 0, 0);
                        acc1 = __builtin_amdgcn_mfma_f32_16x16x32_bf16(k4, qf[1][4], acc1, 0, 0, 0);
                        acc0 = __builtin_amdgcn_mfma_f32_16x16x32_bf16(k5, qf[0][5], acc0, 0, 0, 0);
                        acc1 = __builtin_amdgcn_mfma_f32_16x16x32_bf16(k5, qf[1][5], acc1, 0, 0, 0);
                        acc0 = __builtin_amdgcn_mfma_f32_16x16x32_bf16(k6, qf[0][6], acc0, 0, 0, 0);
                        acc1 = __builtin_amdgcn_mfma_f32_16x16x32_bf16(k6, qf[1][6], acc1, 0, 0, 0);
                        acc0 = __builtin_amdgcn_mfma_f32_16x16x32_bf16(k7, qf[0][7], acc0, 0, 0, 0);
                        acc1 = __builtin_amdgcn_mfma_f32_16x16x32_bf16(k7, qf[1][7], acc1, 0, 0, 0);
                        {
                            const float mx = fmaxf(fmaxf(acc0[0], acc0[1]), fmaxf(acc0[2], acc0[3]));
                            const float mn = fmaxf(mM0, mx);
                            const float sc = __expf(mM0 - mn);
                            const float e0 = __expf(acc0[0] - mn), e1 = __expf(acc0[1] - mn);
                            const float e2 = __expf(acc0[2] - mn), e3 = __expf(acc0[3] - mn);
                            lS0 = lS0 * sc + (e0 + e1 + e2 + e3);
                            oS0 = oS0 * sc + (e0 * vB[0] + e1 * vB[1] + e2 * vB[2] + e3 * vB[3]);
                            mM0 = mn;
                        }
                        {
                            const float mx = fmaxf(fmaxf(acc1[0], acc1[1]), fmaxf(acc1[2], acc1[3]));
                            const float mn = fmaxf(mM1, mx);
                            const float sc = __expf(mM1 - mn);
                            const float e0 = __expf(acc1[0] - mn), e1 = __expf(acc1[1] - mn);
                            const float e2 = __expf(acc1[2] - mn), e3 = __expf(acc1[3] - mn);
                            lS1 = lS1 * sc + (e0 + e1 + e2 + e3);
                            oS1 = oS1 * sc + (e0 * vB[0] + e1 * vB[1] + e2 * vB[2] + e3 * vB[3]);
                            mM1 = mn;
                        }
                    }
                }
#pragma unroll
                for (int d = 16; d < 64; d <<= 1) {
                    {
                        const float m2 = __shfl_xor(mM0, d), l2 = __shfl_xor(lS0, d), o2 = __shfl_xor(oS0, d);
                        const float mn = fmaxf(mM0, m2);
                        const float sa = __expf(mM0 - mn), sb = __expf(m2 - mn);
                        lS0 = lS0 * sa + l2 * sb; oS0 = oS0 * sa + o2 * sb; mM0 = mn;
                    }
                    {
                        const float m2 = __shfl_xor(mM1, d), l2 = __shfl_xor(lS1, d), o2 = __shfl_xor(oS1, d);
                        const float mn = fmaxf(mM1, m2);
                        const float sa = __expf(mM1 - mn), sb = __expf(m2 - mn);
                        lS1 = lS1 * sa + l2 * sb; oS1 = oS1 * sa + o2 * sb; mM1 = mn;
                    }
                }
                if (l < 16) {
                    tri[w][0][l][0] = mM0; tri[w][0][l][1] = lS0; tri[w][0][l][2] = oS0;
                    tri[w][1][l][0] = mM1; tri[w][1][l][1] = lS1; tri[w][1][l][2] = oS1;
                }
                __syncthreads();
                if (tid < 32) {
                    const int m = tid >> 4, qr = tid & 15;
                    float M = tri[0][m][qr][0], L = tri[0][m][qr][1], O = tri[0][m][qr][2];
#pragma unroll
                    for (int ww = 1; ww < 4; ++ww) {
                        const float m2 = tri[ww][m][qr][0], l2 = tri[ww][m][qr][1], o2 = tri[ww][m][qr][2];
                        const float mn = fmaxf(M, m2);
                        const float sa = __expf(M - mn), sb = __expf(m2 - mn);
                        L = L * sa + l2 * sb; O = O * sa + o2 * sb; M = mn;
                    }
                    float val = __fdividef(O, L) + P.ccv[f];
                    val = (val > 0.f) ? val : 0.01f * val;
                    const int b = m0 + m * 16 + qr;
                    P.out[(size_t)b * (TOUT * Fh) + (size_t)t * Fh + f] = val;
                    dinL[m * 16 + qr] = val;
                }
                __syncthreads();
            }
        }
    }
}

extern "C" void kernel_launch(void* const* d_in, const int* in_sizes, int n_in,
                              void* d_out, int out_size, void* d_ws, size_t ws_size,
                              hipStream_t stream)
{
    const float* x     = (const float*)d_in[0];
    const float* eWih0 = (const float*)d_in[1];
    const float* eWhh0 = (const float*)d_in[2];
    const float* ebih0 = (const float*)d_in[3];
    const float* ebhh0 = (const float*)d_in[4];
    const float* eWih1 = (const float*)d_in[5];
    const float* eWhh1 = (const float*)d_in[6];
    const float* ebih1 = (const float*)d_in[7];
    const float* ebhh1 = (const float*)d_in[8];
    const float* dWih  = (const float*)d_in[9];
    const float* dWhh  = (const float*)d_in[10];
    const float* dbih  = (const float*)d_in[11];
    const float* dbhh  = (const float*)d_in[12];
    const float* f1W   = (const float*)d_in[13];
    const float* f1b   = (const float*)d_in[14];
    const float* inW   = (const float*)d_in[15];
    const float* inb   = (const float*)d_in[16];
    const float* oW    = (const float*)d_in[17];
    const float* ob    = (const float*)d_in[18];
    const float* f2W   = (const float*)d_in[19];
    const float* f2b   = (const float*)d_in[20];

    char* base = (char*)d_ws;
    size_t o = 0;
    auto alloc = [&](size_t bytes) { void* p = base + o; o += (bytes + 255) & ~(size_t)255; return p; };
    ushort* h0A = (ushort*)alloc(BH * 2);   // swizzled [4][B][64]
    ushort* h1A = (ushort*)alloc(BH * 2);
    ushort* h0B = (ushort*)alloc(BH * 2);
    ushort* h1B = (ushort*)alloc(BH * 2);
    ushort* hm  = (ushort*)alloc(BH * 2);
    float*  cm  = (float*)alloc(BH * 4);
    ushort* kb0 = (ushort*)alloc(8 * BH * 2);
    ushort* kb1 = (ushort*)alloc(8 * BH * 2);
    float*  vw0 = (float*)alloc((size_t)Fh * Bsz * 4);
    float*  vw1 = (float*)alloc((size_t)Fh * Bsz * 4);
    float*  ubuf = (float*)alloc((size_t)Fh * H * 4);
    float*  dbuf = (float*)alloc(Fh * 4);
    float*  ccb  = (float*)alloc(Fh * 4);
    unsigned* bar = (unsigned*)alloc(3072 * 4);
    ushort* wWhh0 = (ushort*)alloc((size_t)H4 * H * 2);
    ushort* wWih0p= (ushort*)alloc((size_t)H4 * 32 * 2);
    ushort* wWih1 = (ushort*)alloc((size_t)H4 * H * 2);
    ushort* wWhh1 = (ushort*)alloc((size_t)H4 * H * 2);
    ushort* wdWhh = (ushort*)alloc((size_t)8 * H4 * H * 2);
    ushort* wf1W  = (ushort*)alloc((size_t)8 * H * H * 2);
    ushort* winW  = (ushort*)alloc((size_t)8 * 768 * H * 2);

    const dim3 blk(256);

    // zero all four h ping-pong buffers (skew reads them as step "-1") + bar
    hipMemsetAsync(d_ws, 0, BH * 2 * 4, stream);
    hipMemsetAsync(bar, 0, 3072 * 4, stream);

    cast_f32_bf16<<<dim3(512), blk, 0, stream>>>(eWhh0, wWhh0, H4 * H);
    cast_f32_bf16<<<dim3(512), blk, 0, stream>>>(eWih1, wWih1, H4 * H);
    cast_f32_bf16<<<dim3(512), blk, 0, stream>>>(eWhh1, wWhh1, H4 * H);
    cast_pad_wih0<<<dim3(128), blk, 0, stream>>>(eWih0, wWih0p);
    cast_f32_bf16<<<dim3(1024), blk, 0, stream>>>(dWhh, wdWhh, 8 * H4 * H);
    cast_f32_bf16<<<dim3(512), blk, 0, stream>>>(f1W, wf1W, 8 * H * H);
    cast_f32_bf16<<<dim3(1024), blk, 0, stream>>>(inW, winW, 8 * 768 * H);
    precompute_kernel<<<dim3(8), blk, 0, stream>>>(oW, ob, f2W, f2b, inW, inb,
                                                   ubuf, dbuf, ccb);

    MP P;
    P.x = x; P.ebih0 = ebih0; P.ebhh0 = ebhh0; P.ebih1 = ebih1; P.ebhh1 = ebhh1;
    P.Whh0 = wWhh0; P.Wih0p = wWih0p; P.Wih1 = wWih1; P.Whh1 = wWhh1;
    P.h0A = h0A; P.h0B = h0B; P.h1A = h1A; P.h1B = h1B;
    P.hm = hm; P.cm = cm;
    P.dWhh = wdWhh; P.f1Wb = wf1W; P.inWb = winW;
    P.dWih = dWih; P.dbih = dbih; P.dbhh = dbhh; P.f1b = f1b; P.inb = inb;
    P.u = ubuf; P.dconst = dbuf; P.ccv = ccb;
    P.kb0 = kb0; P.kb1 = kb1; P.vw0 = vw0; P.vw1 = vw1;
    P.out = (float*)d_out; P.bar = bar;

    mega5<<<dim3(256), blk, 0, stream>>>(P);

    (void)in_sizes; (void)n_in; (void)out_size; (void)ws_size;
}

// Round 12
// 3206.232 us; speedup vs baseline: 1.1503x; 1.1503x over previous
//
#include <hip/hip_runtime.h>
#include <math.h>

#define H 256
#define H4 1024
#define Bsz 1024
#define TIN 168
#define TOUT 24
#define Fh 8
#define XROW (TIN*Fh)
#define BH ((size_t)Bsz * H)          // 262144
#define SL32 ((size_t)Bsz * 32)       // elems per slice block of swizzled h

typedef __attribute__((ext_vector_type(8))) short bf16x8;
typedef __attribute__((ext_vector_type(4))) float f32x4;

__device__ __forceinline__ ushort f2bf(float f) {
    union { float f; unsigned u; } v; v.f = f;
    unsigned r = v.u + 0x7fff + ((v.u >> 16) & 1);
    return (ushort)(r >> 16);
}
__device__ __forceinline__ float bf2f(ushort u) {
    union { unsigned u; float f; } v; v.u = ((unsigned)u) << 16;
    return v.f;
}
__device__ __forceinline__ float sigmf(float x) {
    return __fdividef(1.0f, 1.0f + __expf(-x));
}
__device__ __forceinline__ float tanhf_(float x) {
    const float e = __expf(-2.0f * fabsf(x));
    const float t = __fdividef(1.0f - e, 1.0f + e);
    return copysignf(t, x);
}

// ---- sc0sc1 (MALL, cross-XCD coherent) helpers ----
__device__ __forceinline__ void load_coh8(const ushort* p0, const ushort* p1,
                                          const ushort* p2, const ushort* p3,
                                          const ushort* p4, const ushort* p5,
                                          const ushort* p6, const ushort* p7,
                                          f32x4& a, f32x4& b, f32x4& c, f32x4& d,
                                          f32x4& e, f32x4& f, f32x4& g, f32x4& h)
{
    asm volatile(
        "global_load_dwordx4 %0, %8, off sc0 sc1\n\t"
        "global_load_dwordx4 %1, %9, off sc0 sc1\n\t"
        "global_load_dwordx4 %2, %10, off sc0 sc1\n\t"
        "global_load_dwordx4 %3, %11, off sc0 sc1\n\t"
        "global_load_dwordx4 %4, %12, off sc0 sc1\n\t"
        "global_load_dwordx4 %5, %13, off sc0 sc1\n\t"
        "global_load_dwordx4 %6, %14, off sc0 sc1\n\t"
        "global_load_dwordx4 %7, %15, off sc0 sc1\n\t"
        "s_waitcnt vmcnt(0)"
        : "=&v"(a), "=&v"(b), "=&v"(c), "=&v"(d),
          "=&v"(e), "=&v"(f), "=&v"(g), "=&v"(h)
        : "v"(p0), "v"(p1), "v"(p2), "v"(p3), "v"(p4), "v"(p5), "v"(p6), "v"(p7)
        : "memory");
}
__device__ __forceinline__ void load_coh4f(const float* p0, const float* p1,
                                           const float* p2, const float* p3,
                                           float& a, float& b, float& c, float& d)
{
    asm volatile(
        "global_load_dword %0, %4, off sc0 sc1\n\t"
        "global_load_dword %1, %5, off sc0 sc1\n\t"
        "global_load_dword %2, %6, off sc0 sc1\n\t"
        "global_load_dword %3, %7, off sc0 sc1\n\t"
        "s_waitcnt vmcnt(0)"
        : "=&v"(a), "=&v"(b), "=&v"(c), "=&v"(d)
        : "v"(p0), "v"(p1), "v"(p2), "v"(p3)
        : "memory");
}
__device__ __forceinline__ void load_coh16Bx(const ushort* p, f32x4& v) {
    asm volatile("global_load_dwordx4 %0, %1, off sc0 sc1\n\ts_waitcnt vmcnt(0)"
                 : "=&v"(v) : "v"(p) : "memory");
}
__device__ __forceinline__ void store_coh8B(ushort* p, uint2 v) {
    asm volatile("global_store_dwordx2 %0, %1, off sc0 sc1"
                 :: "v"(p), "v"(v) : "memory");
}
__device__ __forceinline__ void store_coh16B(float* p, f32x4 v) {
    asm volatile("global_store_dwordx4 %0, %1, off sc0 sc1"
                 :: "v"(p), "v"(v) : "memory");
}

// relaxed-atomic barrier (no acquire/release -> no L2 invalidation). R6-proven.
__device__ __forceinline__ void gbar(unsigned* cnt, unsigned target) {
    asm volatile("s_waitcnt vmcnt(0)" ::: "memory");
    __syncthreads();
    if (threadIdx.x == 0) {
        __hip_atomic_fetch_add(cnt, 1u, __ATOMIC_RELAXED, __HIP_MEMORY_SCOPE_AGENT);
        int sp = 0;
        while (__hip_atomic_fetch_add(cnt, 0u, __ATOMIC_RELAXED,
                                      __HIP_MEMORY_SCOPE_AGENT) < target) {
            __builtin_amdgcn_s_sleep(2);
            if (++sp > 20000) break;   // failsafe: fails absmax, never hangs
        }
    }
    __syncthreads();
    asm volatile("" ::: "memory");
}

__global__ __launch_bounds__(256)
void cast_f32_bf16(const float* __restrict__ in, ushort* __restrict__ out, int n) {
    int i = blockIdx.x * 256 + threadIdx.x;
    const int stride = gridDim.x * 256;
    for (; i < n; i += stride) out[i] = f2bf(in[i]);
}

__global__ __launch_bounds__(256)
void cast_pad_wih0(const float* __restrict__ in, ushort* __restrict__ out) {
    const int idx = blockIdx.x * 256 + threadIdx.x;
    const int row = idx >> 5, c = idx & 31;
    out[idx] = (c < 8) ? f2bf(in[row * 8 + c]) : (ushort)0;
}

__global__ __launch_bounds__(256)
void precompute_kernel(const float* __restrict__ oW, const float* __restrict__ ob,
                       const float* __restrict__ f2W, const float* __restrict__ f2b,
                       const float* __restrict__ inW, const float* __restrict__ inb,
                       float* __restrict__ u, float* __restrict__ dconst,
                       float* __restrict__ ccv)
{
    __shared__ float wsh[256];
    const int f = blockIdx.x;
    const int tid = threadIdx.x;
    float s = 0.f;
    for (int i = 0; i < 256; ++i)
        s += f2W[f * 256 + i] * oW[(size_t)f * 65536 + (size_t)i * 256 + tid];
    wsh[tid] = s;
    __syncthreads();
    float su = 0.f;
    for (int n = 0; n < 256; ++n)
        su += wsh[n] * inW[(size_t)f * 768 * 256 + (size_t)(512 + n) * 256 + tid];
    u[f * 256 + tid] = su;
    if (tid == 0) {
        float dd = 0.f, cc = 0.f;
        for (int n = 0; n < 256; ++n) dd += wsh[n] * inb[f * 768 + 512 + n];
        for (int i = 0; i < 256; ++i) cc += ob[f * 256 + i] * f2W[f * 256 + i];
        dconst[f] = dd;
        ccv[f] = cc + f2b[f];
    }
}

struct MP {
    const float *x, *ebih0, *ebhh0, *ebih1, *ebhh1;
    const ushort *Whh0, *Wih0p, *Wih1, *Whh1;
    ushort *h0A, *h0B, *h1A, *h1B, *hm;
    float *cm;
    const ushort *dWhh, *f1Wb, *inWb;
    const float *dWih, *dbih, *dbhh, *f1b, *inb, *u, *dconst, *ccv;
    ushort *kb0, *kb1;
    float *vw0, *vw1, *out;
    unsigned *bar;
};

// ---------------------------------------------------------------------------
// One persistent kernel — exact R9 structure (best known: 3237us, stable).
// ENCODER (pipeline-skewed): phase i computes L0(i) [i<TIN] and L1(i-1) [i>=1];
// ONE 32KB MALL stage + ONE 8-WG barrier per phase. x-load issued BEFORE the
// stage asm so its latency overlaps the MALL wait (only change vs R9).
// DECODER: f pinned to XCD=bid&7; h in LDS, c in regs, din in LDS; k/vw via
// XCD-local L2 (sc0); attn k-loads batched 2-kf per vmcnt stall.
// ---------------------------------------------------------------------------
__global__ __launch_bounds__(256, 1)
void mega6(MP P)
{
    __shared__ ushort SA[32][264];
    __shared__ ushort SC[32][264];
    __shared__ float pre0[4][32][36];
    __shared__ float pre1[4][32][36];
    __shared__ ushort xL[32][32];
    __shared__ ushort h2s[32][264];
    __shared__ ushort as2[32][264];
    __shared__ ushort qs[32][264];
    __shared__ float tri[4][2][16][3];
    __shared__ float dinL[32];

    const int bid = blockIdx.x;
    const int tid = threadIdx.x;
    const int l = tid & 63, w = tid >> 6;
    const int lr = l & 15, lq = l >> 4, lk = lq * 8;

    // ======================= ENCODER (skewed) =======================
    {
        const int grp = bid >> 3, wgi = bid & 7;
        const int rowbase = grp * 32;
        const int ub = wgi * 32;
        unsigned* cnt = P.bar + grp * 32;
        const int g = w;                       // wave = gate
        const int sS = tid >> 5, sR = tid & 31;

        for (int e = tid; e < 32 * 32; e += 256) (&xL[0][0])[e] = 0;

        const int crow = tid >> 3;
        const int cu = (tid & 7) * 4;
        float c0v[4] = {0,0,0,0}, c1v[4] = {0,0,0,0};
        float h0v[4] = {0,0,0,0}, h1v[4] = {0,0,0,0};

        float b0s[2], b1s[2];
#pragma unroll
        for (int n = 0; n < 2; ++n) {
            const int j = ub + n * 16 + lr;
            b0s[n] = P.ebih0[g * H + j] + P.ebhh0[g * H + j];
            b1s[n] = P.ebih1[g * H + j] + P.ebhh1[g * H + j];
        }
        unsigned bph = 0;
        __syncthreads();

        for (int i = 0; i <= TIN; ++i) {
            ushort*       h0wb = (i & 1) ? P.h0B : P.h0A;
            const ushort* h0rb = (i & 1) ? P.h0A : P.h0B;
            ushort*       h1wb = (i & 1) ? P.h1A : P.h1B;
            const ushort* h1rb = (i & 1) ? P.h1B : P.h1A;

            {   // stage SA <- h0[i-1], SC <- h1[i-2]; x-load issued FIRST so
                // its latency hides under the MALL vmcnt(0).
                float xv = 0.f;
                if (i < TIN)
                    xv = P.x[(size_t)(rowbase + (tid >> 3)) * XROW + i * Fh + (tid & 7)];
                const ushort* s0 = h0rb + sS * SL32 + (size_t)(rowbase + sR) * 32;
                const ushort* s1 = h1rb + sS * SL32 + (size_t)(rowbase + sR) * 32;
                f32x4 a0, a1, a2, a3, b0, b1, b2, b3;
                load_coh8(s0, s0 + 8, s0 + 16, s0 + 24,
                          s1, s1 + 8, s1 + 16, s1 + 24,
                          a0, a1, a2, a3, b0, b1, b2, b3);
                *(f32x4*)&SA[sR][sS * 32 + 0]  = a0;
                *(f32x4*)&SA[sR][sS * 32 + 8]  = a1;
                *(f32x4*)&SA[sR][sS * 32 + 16] = a2;
                *(f32x4*)&SA[sR][sS * 32 + 24] = a3;
                *(f32x4*)&SC[sR][sS * 32 + 0]  = b0;
                *(f32x4*)&SC[sR][sS * 32 + 8]  = b1;
                *(f32x4*)&SC[sR][sS * 32 + 16] = b2;
                *(f32x4*)&SC[sR][sS * 32 + 24] = b3;
                if (i < TIN)
                    xL[tid >> 3][tid & 7] = f2bf(xv);
            }
            __syncthreads();

            // fragment loads (SA shared by L0 and L1)
            bf16x8 aS[2][8], aC[2][8], ax[2];
#pragma unroll
            for (int m = 0; m < 2; ++m) {
#pragma unroll
                for (int k = 0; k < 8; ++k) {
                    aS[m][k] = *(const bf16x8*)&SA[m * 16 + lr][k * 32 + lk];
                    aC[m][k] = *(const bf16x8*)&SC[m * 16 + lr][k * 32 + lk];
                }
                ax[m] = *(const bf16x8*)&xL[m * 16 + lr][lk];
            }

            if (i < TIN) {  // L0(i): gate g = h0[i-1]@Whh0^T + x(i)@Wih0p^T
                f32x4 acc[2][2] = {};
#pragma unroll
                for (int n = 0; n < 2; ++n) {
                    const ushort* wp = P.Whh0 + (size_t)(g * H + ub + n * 16 + lr) * H + lk;
#pragma unroll
                    for (int k = 0; k < 8; ++k) {
                        const bf16x8 b8 = *(const bf16x8*)(wp + k * 32);
                        acc[0][n] = __builtin_amdgcn_mfma_f32_16x16x32_bf16(aS[0][k], b8, acc[0][n], 0, 0, 0);
                        acc[1][n] = __builtin_amdgcn_mfma_f32_16x16x32_bf16(aS[1][k], b8, acc[1][n], 0, 0, 0);
                    }
                    const bf16x8 bx = *(const bf16x8*)(P.Wih0p + (size_t)(g * H + ub + n * 16 + lr) * 32 + lk);
                    acc[0][n] = __builtin_amdgcn_mfma_f32_16x16x32_bf16(ax[0], bx, acc[0][n], 0, 0, 0);
                    acc[1][n] = __builtin_amdgcn_mfma_f32_16x16x32_bf16(ax[1], bx, acc[1][n], 0, 0, 0);
                }
#pragma unroll
                for (int m = 0; m < 2; ++m)
#pragma unroll
                    for (int n = 0; n < 2; ++n)
#pragma unroll
                        for (int r = 0; r < 4; ++r)
                            pre0[g][m * 16 + lq * 4 + r][n * 16 + lr] = acc[m][n][r] + b0s[n];
            }
            if (i >= 1) {   // L1(i-1): gate g = h0[i-1]@Wih1^T + h1[i-2]@Whh1^T
                f32x4 acc[2][2] = {};
#pragma unroll
                for (int n = 0; n < 2; ++n) {
                    const ushort* w1 = P.Wih1 + (size_t)(g * H + ub + n * 16 + lr) * H + lk;
                    const ushort* w2 = P.Whh1 + (size_t)(g * H + ub + n * 16 + lr) * H + lk;
#pragma unroll
                    for (int k = 0; k < 8; ++k) {
                        const bf16x8 b1 = *(const bf16x8*)(w1 + k * 32);
                        acc[0][n] = __builtin_amdgcn_mfma_f32_16x16x32_bf16(aS[0][k], b1, acc[0][n], 0, 0, 0);
                        acc[1][n] = __builtin_amdgcn_mfma_f32_16x16x32_bf16(aS[1][k], b1, acc[1][n], 0, 0, 0);
                        const bf16x8 b2 = *(const bf16x8*)(w2 + k * 32);
                        acc[0][n] = __builtin_amdgcn_mfma_f32_16x16x32_bf16(aC[0][k], b2, acc[0][n], 0, 0, 0);
                        acc[1][n] = __builtin_amdgcn_mfma_f32_16x16x32_bf16(aC[1][k], b2, acc[1][n], 0, 0, 0);
                    }
                }
#pragma unroll
                for (int m = 0; m < 2; ++m)
#pragma unroll
                    for (int n = 0; n < 2; ++n)
#pragma unroll
                        for (int r = 0; r < 4; ++r)
                            pre1[g][m * 16 + lq * 4 + r][n * 16 + lr] = acc[m][n][r] + b1s[n];
            }
            __syncthreads();

            if (i < TIN) {  // c0/h0 update + store slice
                const f32x4 pi = *(const f32x4*)&pre0[0][crow][cu];
                const f32x4 pf = *(const f32x4*)&pre0[1][crow][cu];
                const f32x4 pg = *(const f32x4*)&pre0[2][crow][cu];
                const f32x4 po = *(const f32x4*)&pre0[3][crow][cu];
#pragma unroll
                for (int j = 0; j < 4; ++j) {
                    const float ig = sigmf(pi[j]);
                    const float fg = sigmf(pf[j]);
                    const float gg = tanhf_(pg[j]);
                    const float og = sigmf(po[j]);
                    c0v[j] = fg * c0v[j] + ig * gg;
                    h0v[j] = og * tanhf_(c0v[j]);
                }
                uint2 hp;
                hp.x = (unsigned)f2bf(h0v[0]) | ((unsigned)f2bf(h0v[1]) << 16);
                hp.y = (unsigned)f2bf(h0v[2]) | ((unsigned)f2bf(h0v[3]) << 16);
                store_coh8B(h0wb + wgi * SL32 + (size_t)(rowbase + crow) * 32 + cu, hp);
            }
            if (i >= 1) {   // c1/h1 update + store slice
                const f32x4 pi = *(const f32x4*)&pre1[0][crow][cu];
                const f32x4 pf = *(const f32x4*)&pre1[1][crow][cu];
                const f32x4 pg = *(const f32x4*)&pre1[2][crow][cu];
                const f32x4 po = *(const f32x4*)&pre1[3][crow][cu];
#pragma unroll
                for (int j = 0; j < 4; ++j) {
                    const float ig = sigmf(pi[j]);
                    const float fg = sigmf(pf[j]);
                    const float gg = tanhf_(pg[j]);
                    const float og = sigmf(po[j]);
                    c1v[j] = fg * c1v[j] + ig * gg;
                    h1v[j] = og * tanhf_(c1v[j]);
                }
                uint2 hp;
                hp.x = (unsigned)f2bf(h1v[0]) | ((unsigned)f2bf(h1v[1]) << 16);
                hp.y = (unsigned)f2bf(h1v[2]) | ((unsigned)f2bf(h1v[3]) << 16);
                store_coh8B(h1wb + wgi * SL32 + (size_t)(rowbase + crow) * 32 + cu, hp);
            }
            gbar(cnt, ++bph * 8u);
        }
        // tail: hm/cm from final registers
        {
            uint2 hp;
            hp.x = (unsigned)f2bf(0.5f * (h0v[0] + h1v[0]))
                 | ((unsigned)f2bf(0.5f * (h0v[1] + h1v[1])) << 16);
            hp.y = (unsigned)f2bf(0.5f * (h0v[2] + h1v[2]))
                 | ((unsigned)f2bf(0.5f * (h0v[3] + h1v[3])) << 16);
            store_coh8B(P.hm + (size_t)(rowbase + crow) * 256 + ub + cu, hp);
            f32x4 cv;
#pragma unroll
            for (int j = 0; j < 4; ++j) cv[j] = 0.5f * (c0v[j] + c1v[j]);
            store_coh16B(P.cm + (size_t)(rowbase + crow) * 256 + ub + cu, cv);
        }
    }
    gbar(P.bar + 2048, 256u);   // grid barrier: hm/cm visible at MALL

    // ======================= DECODER =======================
    {
        const int f = bid & 7, mb = bid >> 3;  // XCD = bid%8 = f
        const int m0 = mb * 32;

        // t=0 staging: h2s <- hm (MALL)
#pragma unroll
        for (int it = 0; it < 4; ++it) {
            const int idx = tid + it * 256;
            const int r = idx >> 5, c16 = (idx & 31) * 8;
            f32x4 v0;
            load_coh16Bx(P.hm + (size_t)(m0 + r) * 256 + c16, v0);
            *(f32x4*)&h2s[r][c16] = v0;
        }
        // c regs <- cm (MALL)
        float cd[2][4][4];
#pragma unroll
        for (int m = 0; m < 2; ++m)
#pragma unroll
            for (int jt = 0; jt < 4; ++jt) {
                const float* pc = P.cm + (size_t)(m0 + m * 16 + lq * 4) * 256
                                + (w * 64 + jt * 16 + lr);
                load_coh4f(pc, pc + 256, pc + 512, pc + 768,
                           cd[m][jt][0], cd[m][jt][1], cd[m][jt][2], cd[m][jt][3]);
            }
        float bsum[4][4], wxr[4][4];
#pragma unroll
        for (int jt = 0; jt < 4; ++jt)
#pragma unroll
            for (int g = 0; g < 4; ++g) {
                const int j = w * 64 + jt * 16 + lr;
                bsum[jt][g] = P.dbih[f * H4 + g * H + j] + P.dbhh[f * H4 + g * H + j];
                wxr[jt][g] = P.dWih[f * H4 + g * H + j];
            }
        __syncthreads();

        unsigned* fcnt = P.bar + 1024 + f * 32;

        for (int t = 0; t < TOUT; ++t) {
            ushort* kcur = (t & 1) ? P.kb1 : P.kb0;
            float* vwcur = (t & 1) ? P.vw1 : P.vw0;

            float xiv[2][4];
#pragma unroll
            for (int m = 0; m < 2; ++m)
#pragma unroll
                for (int r = 0; r < 4; ++r) {
                    const int row = m * 16 + lq * 4 + r;
                    xiv[m][r] = (t == 0)
                        ? P.x[(size_t)(m0 + row) * XROW + (TIN - 1) * Fh + f]
                        : dinL[row];
                }
            // ---- LSTM (h from LDS, c in regs) ----
            bf16x8 af[2][8];
#pragma unroll
            for (int m = 0; m < 2; ++m)
#pragma unroll
                for (int k = 0; k < 8; ++k)
                    af[m][k] = *(const bf16x8*)&h2s[m * 16 + lr][k * 32 + lk];
            __syncthreads();
            const ushort* Wb = P.dWhh + (size_t)f * (H4 * H);
#pragma unroll 1
            for (int jt = 0; jt < 4; ++jt) {
                const int j = w * 64 + jt * 16 + lr;
                f32x4 acc[4][2] = {};
#pragma unroll
                for (int g = 0; g < 4; ++g) {
                    const ushort* wp = Wb + (size_t)(g * H + j) * H + lk;
#pragma unroll
                    for (int k = 0; k < 8; ++k) {
                        const bf16x8 b8 = *(const bf16x8*)(wp + k * 32);
                        acc[g][0] = __builtin_amdgcn_mfma_f32_16x16x32_bf16(af[0][k], b8, acc[g][0], 0, 0, 0);
                        acc[g][1] = __builtin_amdgcn_mfma_f32_16x16x32_bf16(af[1][k], b8, acc[g][1], 0, 0, 0);
                    }
                }
#pragma unroll
                for (int m = 0; m < 2; ++m)
#pragma unroll
                    for (int r = 0; r < 4; ++r) {
                        const int row = m * 16 + lq * 4 + r;
                        const float xi = xiv[m][r];
                        const float ig = sigmf(acc[0][m][r] + bsum[jt][0] + xi * wxr[jt][0]);
                        const float fg = sigmf(acc[1][m][r] + bsum[jt][1] + xi * wxr[jt][1]);
                        const float gg = tanhf_(acc[2][m][r] + bsum[jt][2] + xi * wxr[jt][2]);
                        const float og = sigmf(acc[3][m][r] + bsum[jt][3] + xi * wxr[jt][3]);
                        const float cn = fg * cd[m][jt][r] + ig * gg;
                        cd[m][jt][r] = cn;
                        h2s[row][j] = f2bf(og * tanhf_(cn));
                    }
            }
            __syncthreads();
            // ---- fc1 ----
            bf16x8 a2[2][8];
#pragma unroll
            for (int m = 0; m < 2; ++m)
#pragma unroll
                for (int k = 0; k < 8; ++k)
                    a2[m][k] = *(const bf16x8*)&h2s[m * 16 + lr][k * 32 + lk];
            const ushort* Wf = P.f1Wb + (size_t)f * H * H;
#pragma unroll 1
            for (int nt = 0; nt < 4; ++nt) {
                const int n = w * 64 + nt * 16 + lr;
                f32x4 acc0 = {}, acc1 = {};
                const ushort* wp = Wf + (size_t)n * H + lk;
#pragma unroll
                for (int k = 0; k < 8; ++k) {
                    const bf16x8 b8 = *(const bf16x8*)(wp + k * 32);
                    acc0 = __builtin_amdgcn_mfma_f32_16x16x32_bf16(a2[0][k], b8, acc0, 0, 0, 0);
                    acc1 = __builtin_amdgcn_mfma_f32_16x16x32_bf16(a2[1][k], b8, acc1, 0, 0, 0);
                }
                const float bv = P.f1b[f * H + n];
#pragma unroll
                for (int r = 0; r < 4; ++r) {
                    float v0 = acc0[r] + bv; v0 = (v0 > 0.f) ? v0 : 0.01f * v0;
                    as2[lq * 4 + r][n] = f2bf(v0);
                    float v1 = acc1[r] + bv; v1 = (v1 > 0.f) ? v1 : 0.01f * v1;
                    as2[16 + lq * 4 + r][n] = f2bf(v1);
                }
            }
            __syncthreads();
            // ---- q (LDS) / k (global L2) projection ----
            bf16x8 a3[2][8];
#pragma unroll
            for (int m = 0; m < 2; ++m)
#pragma unroll
                for (int k = 0; k < 8; ++k)
                    a3[m][k] = *(const bf16x8*)&as2[m * 16 + lr][k * 32 + lk];
            const ushort* Wi = P.inWb + (size_t)f * 768 * H;
#pragma unroll 1
            for (int nt = 0; nt < 8; ++nt) {
                const int n0 = w * 128 + nt * 16;
                f32x4 acc0 = {}, acc1 = {};
                const ushort* wp = Wi + (size_t)(n0 + lr) * H + lk;
#pragma unroll
                for (int k = 0; k < 8; ++k) {
                    const bf16x8 b8 = *(const bf16x8*)(wp + k * 32);
                    acc0 = __builtin_amdgcn_mfma_f32_16x16x32_bf16(a3[0][k], b8, acc0, 0, 0, 0);
                    acc1 = __builtin_amdgcn_mfma_f32_16x16x32_bf16(a3[1][k], b8, acc1, 0, 0, 0);
                }
                const float bv = P.inb[f * 768 + n0 + lr];
#pragma unroll
                for (int m = 0; m < 2; ++m)
#pragma unroll
                    for (int r = 0; r < 4; ++r) {
                        const float v = (m ? acc1[r] : acc0[r]) + bv;
                        const int row = m * 16 + lq * 4 + r;
                        if (n0 < 256)
                            qs[row][n0 + lr] = f2bf(v * 0.0625f);
                        else
                            kcur[((size_t)f * Bsz + m0 + row) * H + n0 - 256 + lr] = f2bf(v);
                    }
            }
            // ---- vw ----
            {
                const float4 u4 = *(const float4*)(P.u + f * H + l * 4);
#pragma unroll 1
                for (int rr = 0; rr < 8; ++rr) {
                    const int mloc = w * 8 + rr;
                    const ushort4 a4 = *(const ushort4*)&as2[mloc][l * 4];
                    float s = bf2f(a4.x) * u4.x + bf2f(a4.y) * u4.y
                            + bf2f(a4.z) * u4.z + bf2f(a4.w) * u4.w;
#pragma unroll
                    for (int d = 1; d < 64; d <<= 1) s += __shfl_xor(s, d);
                    if (l == 0) vwcur[f * Bsz + m0 + mloc] = s + P.dconst[f];
                }
            }
            // ---- per-f barrier: k/vw complete in XCD L2 ----
            gbar(fcnt, (unsigned)(t + 1) * 32u);
            // ---- attention (2-kf batched loads: one vmcnt stall per 2 kf) ----
            {
                bf16x8 qf[2][8];
#pragma unroll
                for (int m = 0; m < 2; ++m)
#pragma unroll
                    for (int k = 0; k < 8; ++k)
                        qf[m][k] = *(const bf16x8*)&qs[m * 16 + lr][k * 32 + lk];
                float mM0 = -1e30f, lS0 = 0.f, oS0 = 0.f;
                float mM1 = -1e30f, lS1 = 0.f, oS1 = 0.f;
                const int kb0r = w * 256;
#pragma unroll 1
                for (int kf = 0; kf < 16; kf += 2) {
                    const int kbA = kb0r + kf * 16;
                    const ushort* baseA = kcur + ((size_t)f * Bsz + kbA + lr) * H + lk;
                    const ushort* baseB = baseA + 16 * H;
                    const float* pvA = vwcur + f * Bsz + kbA + lq * 4;
                    const float* pvB = pvA + 16;
                    f32x4 A0, A1, A2, A3, A4, A5, A6, A7;
                    f32x4 B0, B1, B2, B3, B4, B5, B6, B7;
                    f32x4 vA, vB;
                    asm volatile(
                        "global_load_dwordx4 %0, %18, off sc0\n\t"
                        "global_load_dwordx4 %1, %18, off offset:64 sc0\n\t"
                        "global_load_dwordx4 %2, %18, off offset:128 sc0\n\t"
                        "global_load_dwordx4 %3, %18, off offset:192 sc0\n\t"
                        "global_load_dwordx4 %4, %18, off offset:256 sc0\n\t"
                        "global_load_dwordx4 %5, %18, off offset:320 sc0\n\t"
                        "global_load_dwordx4 %6, %18, off offset:384 sc0\n\t"
                        "global_load_dwordx4 %7, %18, off offset:448 sc0\n\t"
                        "global_load_dwordx4 %8, %19, off sc0\n\t"
                        "global_load_dwordx4 %9, %19, off offset:64 sc0\n\t"
                        "global_load_dwordx4 %10, %19, off offset:128 sc0\n\t"
                        "global_load_dwordx4 %11, %19, off offset:192 sc0\n\t"
                        "global_load_dwordx4 %12, %19, off offset:256 sc0\n\t"
                        "global_load_dwordx4 %13, %19, off offset:320 sc0\n\t"
                        "global_load_dwordx4 %14, %19, off offset:384 sc0\n\t"
                        "global_load_dwordx4 %15, %19, off offset:448 sc0\n\t"
                        "global_load_dwordx4 %16, %20, off sc0\n\t"
                        "global_load_dwordx4 %17, %21, off sc0\n\t"
                        "s_waitcnt vmcnt(0)"
                        : "=&v"(A0), "=&v"(A1), "=&v"(A2), "=&v"(A3),
                          "=&v"(A4), "=&v"(A5), "=&v"(A6), "=&v"(A7),
                          "=&v"(B0), "=&v"(B1), "=&v"(B2), "=&v"(B3),
                          "=&v"(B4), "=&v"(B5), "=&v"(B6), "=&v"(B7),
                          "=&v"(vA), "=&v"(vB)
                        : "v"(baseA), "v"(baseB), "v"(pvA), "v"(pvB)
                        : "memory");
                    __builtin_amdgcn_sched_barrier(0);
                    // ---- kf A ----
                    {
                        f32x4 acc0 = {}, acc1 = {};
                        const bf16x8 k0 = *(bf16x8*)&A0, k1 = *(bf16x8*)&A1,
                                     k2 = *(bf16x8*)&A2, k3 = *(bf16x8*)&A3,
                                     k4 = *(bf16x8*)&A4, k5 = *(bf16x8*)&A5,
                                     k6 = *(bf16x8*)&A6, k7 = *(bf16x8*)&A7;
                        acc0 = __builtin_amdgcn_mfma_f32_16x16x32_bf16(k0, qf[0][0], acc0, 0, 0, 0);
                        acc1 = __builtin_amdgcn_mfma_f32_16x16x32_bf16(k0, qf[1][0], acc1, 0, 0, 0);
                        acc0 = __builtin_amdgcn_mfma_f32_16x16x32_bf16(k1, qf[0][1], acc0, 0, 0, 0);
                        acc1 = __builtin_amdgcn_mfma_f32_16x16x32_bf16(k1, qf[1][1], acc1, 0, 0, 0);
                        acc0 = __builtin_amdgcn_mfma_f32_16x16x32_bf16(k2, qf[0][2], acc0, 0, 0, 0);
                        acc1 = __builtin_amdgcn_mfma_f32_16x16x32_bf16(k2, qf[1][2], acc1, 0, 0, 0);
                        acc0 = __builtin_amdgcn_mfma_f32_16x16x32_bf16(k3, qf[0][3], acc0, 0, 0, 0);
                        acc1 = __builtin_amdgcn_mfma_f32_16x16x32_bf16(k3, qf[1][3], acc1, 0, 0, 0);
                        acc0 = __builtin_amdgcn_mfma_f32_16x16x32_bf16(k4, qf[0][4], acc0, 0, 0, 0);
                        acc1 = __builtin_amdgcn_mfma_f32_16x16x32_bf16(k4, qf[1][4], acc1, 0, 0, 0);
                        acc0 = __builtin_amdgcn_mfma_f32_16x16x32_bf16(k5, qf[0][5], acc0, 0, 0, 0);
                        acc1 = __builtin_amdgcn_mfma_f32_16x16x32_bf16(k5, qf[1][5], acc1, 0, 0, 0);
                        acc0 = __builtin_amdgcn_mfma_f32_16x16x32_bf16(k6, qf[0][6], acc0, 0, 0, 0);
                        acc1 = __builtin_amdgcn_mfma_f32_16x16x32_bf16(k6, qf[1][6], acc1, 0, 0, 0);
                        acc0 = __builtin_amdgcn_mfma_f32_16x16x32_bf16(k7, qf[0][7], acc0, 0, 0, 0);
                        acc1 = __builtin_amdgcn_mfma_f32_16x16x32_bf16(k7, qf[1][7], acc1, 0, 0, 0);
                        {
                            const float mx = fmaxf(fmaxf(acc0[0], acc0[1]), fmaxf(acc0[2], acc0[3]));
                            const float mn = fmaxf(mM0, mx);
                            const float sc = __expf(mM0 - mn);
                            const float e0 = __expf(acc0[0] - mn), e1 = __expf(acc0[1] - mn);
                            const float e2 = __expf(acc0[2] - mn), e3 = __expf(acc0[3] - mn);
                            lS0 = lS0 * sc + (e0 + e1 + e2 + e3);
                            oS0 = oS0 * sc + (e0 * vA[0] + e1 * vA[1] + e2 * vA[2] + e3 * vA[3]);
                            mM0 = mn;
                        }
                        {
                            const float mx = fmaxf(fmaxf(acc1[0], acc1[1]), fmaxf(acc1[2], acc1[3]));
                            const float mn = fmaxf(mM1, mx);
                            const float sc = __expf(mM1 - mn);
                            const float e0 = __expf(acc1[0] - mn), e1 = __expf(acc1[1] - mn);
                            const float e2 = __expf(acc1[2] - mn), e3 = __expf(acc1[3] - mn);
                            lS1 = lS1 * sc + (e0 + e1 + e2 + e3);
                            oS1 = oS1 * sc + (e0 * vA[0] + e1 * vA[1] + e2 * vA[2] + e3 * vA[3]);
                            mM1 = mn;
                        }
                    }
                    // ---- kf B ----
                    {
                        f32x4 acc0 = {}, acc1 = {};
                        const bf16x8 k0 = *(bf16x8*)&B0, k1 = *(bf16x8*)&B1,
                                     k2 = *(bf16x8*)&B2, k3 = *(bf16x8*)&B3,
                                     k4 = *(bf16x8*)&B4, k5 = *(bf16x8*)&B5,
                                     k6 = *(bf16x8*)&B6, k7 = *(bf16x8*)&B7;
                        acc0 = __builtin_amdgcn_mfma_f32_16x16x32_bf16(k0, qf[0][0], acc0, 0, 0, 0);
                        acc1 = __builtin_amdgcn_mfma_f32_16x16x32_bf16(k0, qf[1][0], acc1, 0, 0, 0);
                        acc0 = __builtin_amdgcn_mfma_f32_16x16x32_bf16(k1, qf[0][1], acc0, 0, 0, 0);
                        acc1 = __builtin_amdgcn_mfma_f32_16x16x32_bf16(k1, qf[1][1], acc1, 0, 0, 0);
                        acc0 = __builtin_amdgcn_mfma_f32_16x16x32_bf16(k2, qf[0][2], acc0, 0, 0, 0);
                        acc1 = __builtin_amdgcn_mfma_f32_16x16x32_bf16(k2, qf[1][2], acc1, 0, 0, 0);
                        acc0 = __builtin_amdgcn_mfma_f32_16x16x32_bf16(k3, qf[0][3], acc0, 0, 0, 0);
                        acc1 = __builtin_amdgcn_mfma_f32_16x16x32_bf16(k3, qf[1][3], acc1, 0, 0, 0);
                        acc0 = __builtin_amdgcn_mfma_f32_16x16x32_bf16(k4, qf[0][4], acc0, 0, 0, 0);
                        acc1 = __builtin_amdgcn_mfma_f32_16x16x32_bf16(k4, qf[1][4], acc1, 0, 0, 0);
                        acc0 = __builtin_amdgcn_mfma_f32_16x16x32_bf16(k5, qf[0][5], acc0, 0, 0, 0);
                        acc1 = __builtin_amdgcn_mfma_f32_16x16x32_bf16(k5, qf[1][5], acc1, 0, 0, 0);
                        acc0 = __builtin_amdgcn_mfma_f32_16x16x32_bf16(k6, qf[0][6], acc0, 0, 0, 0);
                        acc1 = __builtin_amdgcn_mfma_f32_16x16x32_bf16(k6, qf[1][6], acc1, 0, 0, 0);
                        acc0 = __builtin_amdgcn_mfma_f32_16x16x32_bf16(k7, qf[0][7], acc0, 0, 0, 0);
                        acc1 = __builtin_amdgcn_mfma_f32_16x16x32_bf16(k7, qf[1][7], acc1, 0, 0, 0);
                        {
                            const float mx = fmaxf(fmaxf(acc0[0], acc0[1]), fmaxf(acc0[2], acc0[3]));
                            const float mn = fmaxf(mM0, mx);
                            const float sc = __expf(mM0 - mn);
                            const float e0 = __expf(acc0[0] - mn), e1 = __expf(acc0[1] - mn);
                            const float e2 = __expf(acc0[2] - mn), e3 = __expf(acc0[3] - mn);
                            lS0 = lS0 * sc + (e0 + e1 + e2 + e3);
                            oS0 = oS0 * sc + (e0 * vB[0] + e1 * vB[1] + e2 * vB[2] + e3 * vB[3]);
                            mM0 = mn;
                        }
                        {
                            const float mx = fmaxf(fmaxf(acc1[0], acc1[1]), fmaxf(acc1[2], acc1[3]));
                            const float mn = fmaxf(mM1, mx);
                            const float sc = __expf(mM1 - mn);
                            const float e0 = __expf(acc1[0] - mn), e1 = __expf(acc1[1] - mn);
                            const float e2 = __expf(acc1[2] - mn), e3 = __expf(acc1[3] - mn);
                            lS1 = lS1 * sc + (e0 + e1 + e2 + e3);
                            oS1 = oS1 * sc + (e0 * vB[0] + e1 * vB[1] + e2 * vB[2] + e3 * vB[3]);
                            mM1 = mn;
                        }
                    }
                }
#pragma unroll
                for (int d = 16; d < 64; d <<= 1) {
                    {
                        const float m2 = __shfl_xor(mM0, d), l2 = __shfl_xor(lS0, d), o2 = __shfl_xor(oS0, d);
                        const float mn = fmaxf(mM0, m2);
                        const float sa = __expf(mM0 - mn), sb = __expf(m2 - mn);
                        lS0 = lS0 * sa + l2 * sb; oS0 = oS0 * sa + o2 * sb; mM0 = mn;
                    }
                    {
                        const float m2 = __shfl_xor(mM1, d), l2 = __shfl_xor(lS1, d), o2 = __shfl_xor(oS1, d);
                        const float mn = fmaxf(mM1, m2);
                        const float sa = __expf(mM1 - mn), sb = __expf(m2 - mn);
                        lS1 = lS1 * sa + l2 * sb; oS1 = oS1 * sa + o2 * sb; mM1 = mn;
                    }
                }
                if (l < 16) {
                    tri[w][0][l][0] = mM0; tri[w][0][l][1] = lS0; tri[w][0][l][2] = oS0;
                    tri[w][1][l][0] = mM1; tri[w][1][l][1] = lS1; tri[w][1][l][2] = oS1;
                }
                __syncthreads();
                if (tid < 32) {
                    const int m = tid >> 4, qr = tid & 15;
                    float M = tri[0][m][qr][0], L = tri[0][m][qr][1], O = tri[0][m][qr][2];
#pragma unroll
                    for (int ww = 1; ww < 4; ++ww) {
                        const float m2 = tri[ww][m][qr][0], l2 = tri[ww][m][qr][1], o2 = tri[ww][m][qr][2];
                        const float mn = fmaxf(M, m2);
                        const float sa = __expf(M - mn), sb = __expf(m2 - mn);
                        L = L * sa + l2 * sb; O = O * sa + o2 * sb; M = mn;
                    }
                    float val = __fdividef(O, L) + P.ccv[f];
                    val = (val > 0.f) ? val : 0.01f * val;
                    const int b = m0 + m * 16 + qr;
                    P.out[(size_t)b * (TOUT * Fh) + (size_t)t * Fh + f] = val;
                    dinL[m * 16 + qr] = val;
                }
                __syncthreads();
            }
        }
    }
}

extern "C" void kernel_launch(void* const* d_in, const int* in_sizes, int n_in,
                              void* d_out, int out_size, void* d_ws, size_t ws_size,
                              hipStream_t stream)
{
    const float* x     = (const float*)d_in[0];
    const float* eWih0 = (const float*)d_in[1];
    const float* eWhh0 = (const float*)d_in[2];
    const float* ebih0 = (const float*)d_in[3];
    const float* ebhh0 = (const float*)d_in[4];
    const float* eWih1 = (const float*)d_in[5];
    const float* eWhh1 = (const float*)d_in[6];
    const float* ebih1 = (const float*)d_in[7];
    const float* ebhh1 = (const float*)d_in[8];
    const float* dWih  = (const float*)d_in[9];
    const float* dWhh  = (const float*)d_in[10];
    const float* dbih  = (const float*)d_in[11];
    const float* dbhh  = (const float*)d_in[12];
    const float* f1W   = (const float*)d_in[13];
    const float* f1b   = (const float*)d_in[14];
    const float* inW   = (const float*)d_in[15];
    const float* inb   = (const float*)d_in[16];
    const float* oW    = (const float*)d_in[17];
    const float* ob    = (const float*)d_in[18];
    const float* f2W   = (const float*)d_in[19];
    const float* f2b   = (const float*)d_in[20];

    char* base = (char*)d_ws;
    size_t o = 0;
    auto alloc = [&](size_t bytes) { void* p = base + o; o += (bytes + 255) & ~(size_t)255; return p; };
    ushort* h0A = (ushort*)alloc(BH * 2);   // swizzled [8][B][32]
    ushort* h1A = (ushort*)alloc(BH * 2);
    ushort* h0B = (ushort*)alloc(BH * 2);
    ushort* h1B = (ushort*)alloc(BH * 2);
    ushort* hm  = (ushort*)alloc(BH * 2);
    float*  cm  = (float*)alloc(BH * 4);
    ushort* kb0 = (ushort*)alloc(8 * BH * 2);
    ushort* kb1 = (ushort*)alloc(8 * BH * 2);
    float*  vw0 = (float*)alloc((size_t)Fh * Bsz * 4);
    float*  vw1 = (float*)alloc((size_t)Fh * Bsz * 4);
    float*  ubuf = (float*)alloc((size_t)Fh * H * 4);
    float*  dbuf = (float*)alloc(Fh * 4);
    float*  ccb  = (float*)alloc(Fh * 4);
    unsigned* bar = (unsigned*)alloc(3072 * 4);
    ushort* wWhh0 = (ushort*)alloc((size_t)H4 * H * 2);
    ushort* wWih0p= (ushort*)alloc((size_t)H4 * 32 * 2);
    ushort* wWih1 = (ushort*)alloc((size_t)H4 * H * 2);
    ushort* wWhh1 = (ushort*)alloc((size_t)H4 * H * 2);
    ushort* wdWhh = (ushort*)alloc((size_t)8 * H4 * H * 2);
    ushort* wf1W  = (ushort*)alloc((size_t)8 * H * H * 2);
    ushort* winW  = (ushort*)alloc((size_t)8 * 768 * H * 2);

    const dim3 blk(256);

    // zero all four h ping-pong buffers (skew reads them as step "-1") + bar
    hipMemsetAsync(d_ws, 0, BH * 2 * 4, stream);
    hipMemsetAsync(bar, 0, 3072 * 4, stream);

    cast_f32_bf16<<<dim3(512), blk, 0, stream>>>(eWhh0, wWhh0, H4 * H);
    cast_f32_bf16<<<dim3(512), blk, 0, stream>>>(eWih1, wWih1, H4 * H);
    cast_f32_bf16<<<dim3(512), blk, 0, stream>>>(eWhh1, wWhh1, H4 * H);
    cast_pad_wih0<<<dim3(128), blk, 0, stream>>>(eWih0, wWih0p);
    cast_f32_bf16<<<dim3(1024), blk, 0, stream>>>(dWhh, wdWhh, 8 * H4 * H);
    cast_f32_bf16<<<dim3(512), blk, 0, stream>>>(f1W, wf1W, 8 * H * H);
    cast_f32_bf16<<<dim3(1024), blk, 0, stream>>>(inW, winW, 8 * 768 * H);
    precompute_kernel<<<dim3(8), blk, 0, stream>>>(oW, ob, f2W, f2b, inW, inb,
                                                   ubuf, dbuf, ccb);

    MP P;
    P.x = x; P.ebih0 = ebih0; P.ebhh0 = ebhh0; P.ebih1 = ebih1; P.ebhh1 = ebhh1;
    P.Whh0 = wWhh0; P.Wih0p = wWih0p; P.Wih1 = wWih1; P.Whh1 = wWhh1;
    P.h0A = h0A; P.h0B = h0B; P.h1A = h1A; P.h1B = h1B;
    P.hm = hm; P.cm = cm;
    P.dWhh = wdWhh; P.f1Wb = wf1W; P.inWb = winW;
    P.dWih = dWih; P.dbih = dbih; P.dbhh = dbhh; P.f1b = f1b; P.inb = inb;
    P.u = ubuf; P.dconst = dbuf; P.ccv = ccb;
    P.kb0 = kb0; P.kb1 = kb1; P.vw0 = vw0; P.vw1 = vw1;
    P.out = (float*)d_out; P.bar = bar;

    mega6<<<dim3(256), blk, 0, stream>>>(P);

    (void)in_sizes; (void)n_in; (void)out_size; (void)ws_size;
}

// Round 13
// 3198.488 us; speedup vs baseline: 1.1531x; 1.0024x over previous
//
#include <hip/hip_runtime.h>
#include <math.h>

#define H 256
#define H4 1024
#define Bsz 1024
#define TIN 168
#define TOUT 24
#define Fh 8
#define XROW (TIN*Fh)
#define BH ((size_t)Bsz * H)          // 262144
#define SL32 ((size_t)Bsz * 32)       // elems per slice block of swizzled h

typedef __attribute__((ext_vector_type(8))) short bf16x8;
typedef __attribute__((ext_vector_type(4))) float f32x4;

__device__ __forceinline__ ushort f2bf(float f) {
    union { float f; unsigned u; } v; v.f = f;
    unsigned r = v.u + 0x7fff + ((v.u >> 16) & 1);
    return (ushort)(r >> 16);
}
__device__ __forceinline__ float bf2f(ushort u) {
    union { unsigned u; float f; } v; v.u = ((unsigned)u) << 16;
    return v.f;
}
__device__ __forceinline__ float sigmf(float x) {
    return __fdividef(1.0f, 1.0f + __expf(-x));
}
__device__ __forceinline__ float tanhf_(float x) {
    const float e = __expf(-2.0f * fabsf(x));
    const float t = __fdividef(1.0f - e, 1.0f + e);
    return copysignf(t, x);
}

// ---- sc0sc1 (MALL, cross-XCD coherent) helpers ----
__device__ __forceinline__ void load_coh8(const ushort* p0, const ushort* p1,
                                          const ushort* p2, const ushort* p3,
                                          const ushort* p4, const ushort* p5,
                                          const ushort* p6, const ushort* p7,
                                          f32x4& a, f32x4& b, f32x4& c, f32x4& d,
                                          f32x4& e, f32x4& f, f32x4& g, f32x4& h)
{
    asm volatile(
        "global_load_dwordx4 %0, %8, off sc0 sc1\n\t"
        "global_load_dwordx4 %1, %9, off sc0 sc1\n\t"
        "global_load_dwordx4 %2, %10, off sc0 sc1\n\t"
        "global_load_dwordx4 %3, %11, off sc0 sc1\n\t"
        "global_load_dwordx4 %4, %12, off sc0 sc1\n\t"
        "global_load_dwordx4 %5, %13, off sc0 sc1\n\t"
        "global_load_dwordx4 %6, %14, off sc0 sc1\n\t"
        "global_load_dwordx4 %7, %15, off sc0 sc1\n\t"
        "s_waitcnt vmcnt(0)"
        : "=&v"(a), "=&v"(b), "=&v"(c), "=&v"(d),
          "=&v"(e), "=&v"(f), "=&v"(g), "=&v"(h)
        : "v"(p0), "v"(p1), "v"(p2), "v"(p3), "v"(p4), "v"(p5), "v"(p6), "v"(p7)
        : "memory");
}
__device__ __forceinline__ void load_coh4f(const float* p0, const float* p1,
                                           const float* p2, const float* p3,
                                           float& a, float& b, float& c, float& d)
{
    asm volatile(
        "global_load_dword %0, %4, off sc0 sc1\n\t"
        "global_load_dword %1, %5, off sc0 sc1\n\t"
        "global_load_dword %2, %6, off sc0 sc1\n\t"
        "global_load_dword %3, %7, off sc0 sc1\n\t"
        "s_waitcnt vmcnt(0)"
        : "=&v"(a), "=&v"(b), "=&v"(c), "=&v"(d)
        : "v"(p0), "v"(p1), "v"(p2), "v"(p3)
        : "memory");
}
__device__ __forceinline__ void load_coh16Bx(const ushort* p, f32x4& v) {
    asm volatile("global_load_dwordx4 %0, %1, off sc0 sc1\n\ts_waitcnt vmcnt(0)"
                 : "=&v"(v) : "v"(p) : "memory");
}
__device__ __forceinline__ void store_coh8B(ushort* p, uint2 v) {
    asm volatile("global_store_dwordx2 %0, %1, off sc0 sc1"
                 :: "v"(p), "v"(v) : "memory");
}
__device__ __forceinline__ void store_coh16B(float* p, f32x4 v) {
    asm volatile("global_store_dwordx4 %0, %1, off sc0 sc1"
                 :: "v"(p), "v"(v) : "memory");
}

// barrier v2: arrive = ONE relaxed RMW; poll = plain sc0sc1 LOAD (served fresh
// from MALL, no exclusive-ownership queueing — the R6 fetch_add(0) poll made
// every poller an RMW on the same line, serializing at the MALL bank).
__device__ __forceinline__ void gbar(unsigned* cnt, unsigned target) {
    asm volatile("s_waitcnt vmcnt(0)" ::: "memory");
    __syncthreads();
    if (threadIdx.x == 0) {
        __hip_atomic_fetch_add(cnt, 1u, __ATOMIC_RELAXED, __HIP_MEMORY_SCOPE_AGENT);
        int sp = 0;
        unsigned cur;
        do {
            asm volatile("global_load_dword %0, %1, off sc0 sc1\n\ts_waitcnt vmcnt(0)"
                         : "=v"(cur) : "v"(cnt) : "memory");
            if (cur >= target) break;
            __builtin_amdgcn_s_sleep(1);
        } while (++sp < 40000);   // failsafe: fails absmax, never hangs
    }
    __syncthreads();
    asm volatile("" ::: "memory");
}

__global__ __launch_bounds__(256)
void cast_f32_bf16(const float* __restrict__ in, ushort* __restrict__ out, int n) {
    int i = blockIdx.x * 256 + threadIdx.x;
    const int stride = gridDim.x * 256;
    for (; i < n; i += stride) out[i] = f2bf(in[i]);
}

__global__ __launch_bounds__(256)
void cast_pad_wih0(const float* __restrict__ in, ushort* __restrict__ out) {
    const int idx = blockIdx.x * 256 + threadIdx.x;
    const int row = idx >> 5, c = idx & 31;
    out[idx] = (c < 8) ? f2bf(in[row * 8 + c]) : (ushort)0;
}

__global__ __launch_bounds__(256)
void precompute_kernel(const float* __restrict__ oW, const float* __restrict__ ob,
                       const float* __restrict__ f2W, const float* __restrict__ f2b,
                       const float* __restrict__ inW, const float* __restrict__ inb,
                       float* __restrict__ u, float* __restrict__ dconst,
                       float* __restrict__ ccv)
{
    __shared__ float wsh[256];
    const int f = blockIdx.x;
    const int tid = threadIdx.x;
    float s = 0.f;
    for (int i = 0; i < 256; ++i)
        s += f2W[f * 256 + i] * oW[(size_t)f * 65536 + (size_t)i * 256 + tid];
    wsh[tid] = s;
    __syncthreads();
    float su = 0.f;
    for (int n = 0; n < 256; ++n)
        su += wsh[n] * inW[(size_t)f * 768 * 256 + (size_t)(512 + n) * 256 + tid];
    u[f * 256 + tid] = su;
    if (tid == 0) {
        float dd = 0.f, cc = 0.f;
        for (int n = 0; n < 256; ++n) dd += wsh[n] * inb[f * 768 + 512 + n];
        for (int i = 0; i < 256; ++i) cc += ob[f * 256 + i] * f2W[f * 256 + i];
        dconst[f] = dd;
        ccv[f] = cc + f2b[f];
    }
}

struct MP {
    const float *x, *ebih0, *ebhh0, *ebih1, *ebhh1;
    const ushort *Whh0, *Wih0p, *Wih1, *Whh1;
    ushort *h0A, *h0B, *h1A, *h1B, *hm;
    float *cm;
    const ushort *dWhh, *f1Wb, *inWb;
    const float *dWih, *dbih, *dbhh, *f1b, *inb, *u, *dconst, *ccv;
    ushort *kb0, *kb1;
    float *vw0, *vw1, *out;
    unsigned *bar;
};

// ---------------------------------------------------------------------------
// One persistent kernel — R12 structure, load-poll barrier (only change).
// ---------------------------------------------------------------------------
__global__ __launch_bounds__(256, 1)
void mega7(MP P)
{
    __shared__ ushort SA[32][264];
    __shared__ ushort SC[32][264];
    __shared__ float pre0[4][32][36];
    __shared__ float pre1[4][32][36];
    __shared__ ushort xL[32][32];
    __shared__ ushort h2s[32][264];
    __shared__ ushort as2[32][264];
    __shared__ ushort qs[32][264];
    __shared__ float tri[4][2][16][3];
    __shared__ float dinL[32];

    const int bid = blockIdx.x;
    const int tid = threadIdx.x;
    const int l = tid & 63, w = tid >> 6;
    const int lr = l & 15, lq = l >> 4, lk = lq * 8;

    // ======================= ENCODER (skewed) =======================
    {
        const int grp = bid >> 3, wgi = bid & 7;
        const int rowbase = grp * 32;
        const int ub = wgi * 32;
        unsigned* cnt = P.bar + grp * 32;
        const int g = w;                       // wave = gate
        const int sS = tid >> 5, sR = tid & 31;

        for (int e = tid; e < 32 * 32; e += 256) (&xL[0][0])[e] = 0;

        const int crow = tid >> 3;
        const int cu = (tid & 7) * 4;
        float c0v[4] = {0,0,0,0}, c1v[4] = {0,0,0,0};
        float h0v[4] = {0,0,0,0}, h1v[4] = {0,0,0,0};

        float b0s[2], b1s[2];
#pragma unroll
        for (int n = 0; n < 2; ++n) {
            const int j = ub + n * 16 + lr;
            b0s[n] = P.ebih0[g * H + j] + P.ebhh0[g * H + j];
            b1s[n] = P.ebih1[g * H + j] + P.ebhh1[g * H + j];
        }
        unsigned bph = 0;
        __syncthreads();

        for (int i = 0; i <= TIN; ++i) {
            ushort*       h0wb = (i & 1) ? P.h0B : P.h0A;
            const ushort* h0rb = (i & 1) ? P.h0A : P.h0B;
            ushort*       h1wb = (i & 1) ? P.h1A : P.h1B;
            const ushort* h1rb = (i & 1) ? P.h1B : P.h1A;

            {   // stage SA <- h0[i-1], SC <- h1[i-2]; x-load issued FIRST so
                // its latency hides under the MALL vmcnt(0).
                float xv = 0.f;
                if (i < TIN)
                    xv = P.x[(size_t)(rowbase + (tid >> 3)) * XROW + i * Fh + (tid & 7)];
                const ushort* s0 = h0rb + sS * SL32 + (size_t)(rowbase + sR) * 32;
                const ushort* s1 = h1rb + sS * SL32 + (size_t)(rowbase + sR) * 32;
                f32x4 a0, a1, a2, a3, b0, b1, b2, b3;
                load_coh8(s0, s0 + 8, s0 + 16, s0 + 24,
                          s1, s1 + 8, s1 + 16, s1 + 24,
                          a0, a1, a2, a3, b0, b1, b2, b3);
                *(f32x4*)&SA[sR][sS * 32 + 0]  = a0;
                *(f32x4*)&SA[sR][sS * 32 + 8]  = a1;
                *(f32x4*)&SA[sR][sS * 32 + 16] = a2;
                *(f32x4*)&SA[sR][sS * 32 + 24] = a3;
                *(f32x4*)&SC[sR][sS * 32 + 0]  = b0;
                *(f32x4*)&SC[sR][sS * 32 + 8]  = b1;
                *(f32x4*)&SC[sR][sS * 32 + 16] = b2;
                *(f32x4*)&SC[sR][sS * 32 + 24] = b3;
                if (i < TIN)
                    xL[tid >> 3][tid & 7] = f2bf(xv);
            }
            __syncthreads();

            // fragment loads (SA shared by L0 and L1)
            bf16x8 aS[2][8], aC[2][8], ax[2];
#pragma unroll
            for (int m = 0; m < 2; ++m) {
#pragma unroll
                for (int k = 0; k < 8; ++k) {
                    aS[m][k] = *(const bf16x8*)&SA[m * 16 + lr][k * 32 + lk];
                    aC[m][k] = *(const bf16x8*)&SC[m * 16 + lr][k * 32 + lk];
                }
                ax[m] = *(const bf16x8*)&xL[m * 16 + lr][lk];
            }

            if (i < TIN) {  // L0(i): gate g = h0[i-1]@Whh0^T + x(i)@Wih0p^T
                f32x4 acc[2][2] = {};
#pragma unroll
                for (int n = 0; n < 2; ++n) {
                    const ushort* wp = P.Whh0 + (size_t)(g * H + ub + n * 16 + lr) * H + lk;
#pragma unroll
                    for (int k = 0; k < 8; ++k) {
                        const bf16x8 b8 = *(const bf16x8*)(wp + k * 32);
                        acc[0][n] = __builtin_amdgcn_mfma_f32_16x16x32_bf16(aS[0][k], b8, acc[0][n], 0, 0, 0);
                        acc[1][n] = __builtin_amdgcn_mfma_f32_16x16x32_bf16(aS[1][k], b8, acc[1][n], 0, 0, 0);
                    }
                    const bf16x8 bx = *(const bf16x8*)(P.Wih0p + (size_t)(g * H + ub + n * 16 + lr) * 32 + lk);
                    acc[0][n] = __builtin_amdgcn_mfma_f32_16x16x32_bf16(ax[0], bx, acc[0][n], 0, 0, 0);
                    acc[1][n] = __builtin_amdgcn_mfma_f32_16x16x32_bf16(ax[1], bx, acc[1][n], 0, 0, 0);
                }
#pragma unroll
                for (int m = 0; m < 2; ++m)
#pragma unroll
                    for (int n = 0; n < 2; ++n)
#pragma unroll
                        for (int r = 0; r < 4; ++r)
                            pre0[g][m * 16 + lq * 4 + r][n * 16 + lr] = acc[m][n][r] + b0s[n];
            }
            if (i >= 1) {   // L1(i-1): gate g = h0[i-1]@Wih1^T + h1[i-2]@Whh1^T
                f32x4 acc[2][2] = {};
#pragma unroll
                for (int n = 0; n < 2; ++n) {
                    const ushort* w1 = P.Wih1 + (size_t)(g * H + ub + n * 16 + lr) * H + lk;
                    const ushort* w2 = P.Whh1 + (size_t)(g * H + ub + n * 16 + lr) * H + lk;
#pragma unroll
                    for (int k = 0; k < 8; ++k) {
                        const bf16x8 b1 = *(const bf16x8*)(w1 + k * 32);
                        acc[0][n] = __builtin_amdgcn_mfma_f32_16x16x32_bf16(aS[0][k], b1, acc[0][n], 0, 0, 0);
                        acc[1][n] = __builtin_amdgcn_mfma_f32_16x16x32_bf16(aS[1][k], b1, acc[1][n], 0, 0, 0);
                        const bf16x8 b2 = *(const bf16x8*)(w2 + k * 32);
                        acc[0][n] = __builtin_amdgcn_mfma_f32_16x16x32_bf16(aC[0][k], b2, acc[0][n], 0, 0, 0);
                        acc[1][n] = __builtin_amdgcn_mfma_f32_16x16x32_bf16(aC[1][k], b2, acc[1][n], 0, 0, 0);
                    }
                }
#pragma unroll
                for (int m = 0; m < 2; ++m)
#pragma unroll
                    for (int n = 0; n < 2; ++n)
#pragma unroll
                        for (int r = 0; r < 4; ++r)
                            pre1[g][m * 16 + lq * 4 + r][n * 16 + lr] = acc[m][n][r] + b1s[n];
            }
            __syncthreads();

            if (i < TIN) {  // c0/h0 update + store slice
                const f32x4 pi = *(const f32x4*)&pre0[0][crow][cu];
                const f32x4 pf = *(const f32x4*)&pre0[1][crow][cu];
                const f32x4 pg = *(const f32x4*)&pre0[2][crow][cu];
                const f32x4 po = *(const f32x4*)&pre0[3][crow][cu];
#pragma unroll
                for (int j = 0; j < 4; ++j) {
                    const float ig = sigmf(pi[j]);
                    const float fg = sigmf(pf[j]);
                    const float gg = tanhf_(pg[j]);
                    const float og = sigmf(po[j]);
                    c0v[j] = fg * c0v[j] + ig * gg;
                    h0v[j] = og * tanhf_(c0v[j]);
                }
                uint2 hp;
                hp.x = (unsigned)f2bf(h0v[0]) | ((unsigned)f2bf(h0v[1]) << 16);
                hp.y = (unsigned)f2bf(h0v[2]) | ((unsigned)f2bf(h0v[3]) << 16);
                store_coh8B(h0wb + wgi * SL32 + (size_t)(rowbase + crow) * 32 + cu, hp);
            }
            if (i >= 1) {   // c1/h1 update + store slice
                const f32x4 pi = *(const f32x4*)&pre1[0][crow][cu];
                const f32x4 pf = *(const f32x4*)&pre1[1][crow][cu];
                const f32x4 pg = *(const f32x4*)&pre1[2][crow][cu];
                const f32x4 po = *(const f32x4*)&pre1[3][crow][cu];
#pragma unroll
                for (int j = 0; j < 4; ++j) {
                    const float ig = sigmf(pi[j]);
                    const float fg = sigmf(pf[j]);
                    const float gg = tanhf_(pg[j]);
                    const float og = sigmf(po[j]);
                    c1v[j] = fg * c1v[j] + ig * gg;
                    h1v[j] = og * tanhf_(c1v[j]);
                }
                uint2 hp;
                hp.x = (unsigned)f2bf(h1v[0]) | ((unsigned)f2bf(h1v[1]) << 16);
                hp.y = (unsigned)f2bf(h1v[2]) | ((unsigned)f2bf(h1v[3]) << 16);
                store_coh8B(h1wb + wgi * SL32 + (size_t)(rowbase + crow) * 32 + cu, hp);
            }
            gbar(cnt, ++bph * 8u);
        }
        // tail: hm/cm from final registers
        {
            uint2 hp;
            hp.x = (unsigned)f2bf(0.5f * (h0v[0] + h1v[0]))
                 | ((unsigned)f2bf(0.5f * (h0v[1] + h1v[1])) << 16);
            hp.y = (unsigned)f2bf(0.5f * (h0v[2] + h1v[2]))
                 | ((unsigned)f2bf(0.5f * (h0v[3] + h1v[3])) << 16);
            store_coh8B(P.hm + (size_t)(rowbase + crow) * 256 + ub + cu, hp);
            f32x4 cv;
#pragma unroll
            for (int j = 0; j < 4; ++j) cv[j] = 0.5f * (c0v[j] + c1v[j]);
            store_coh16B(P.cm + (size_t)(rowbase + crow) * 256 + ub + cu, cv);
        }
    }
    gbar(P.bar + 2048, 256u);   // grid barrier: hm/cm visible at MALL

    // ======================= DECODER =======================
    {
        const int f = bid & 7, mb = bid >> 3;  // XCD = bid%8 = f
        const int m0 = mb * 32;

        // t=0 staging: h2s <- hm (MALL)
#pragma unroll
        for (int it = 0; it < 4; ++it) {
            const int idx = tid + it * 256;
            const int r = idx >> 5, c16 = (idx & 31) * 8;
            f32x4 v0;
            load_coh16Bx(P.hm + (size_t)(m0 + r) * 256 + c16, v0);
            *(f32x4*)&h2s[r][c16] = v0;
        }
        // c regs <- cm (MALL)
        float cd[2][4][4];
#pragma unroll
        for (int m = 0; m < 2; ++m)
#pragma unroll
            for (int jt = 0; jt < 4; ++jt) {
                const float* pc = P.cm + (size_t)(m0 + m * 16 + lq * 4) * 256
                                + (w * 64 + jt * 16 + lr);
                load_coh4f(pc, pc + 256, pc + 512, pc + 768,
                           cd[m][jt][0], cd[m][jt][1], cd[m][jt][2], cd[m][jt][3]);
            }
        float bsum[4][4], wxr[4][4];
#pragma unroll
        for (int jt = 0; jt < 4; ++jt)
#pragma unroll
            for (int g = 0; g < 4; ++g) {
                const int j = w * 64 + jt * 16 + lr;
                bsum[jt][g] = P.dbih[f * H4 + g * H + j] + P.dbhh[f * H4 + g * H + j];
                wxr[jt][g] = P.dWih[f * H4 + g * H + j];
            }
        __syncthreads();

        unsigned* fcnt = P.bar + 1024 + f * 32;

        for (int t = 0; t < TOUT; ++t) {
            ushort* kcur = (t & 1) ? P.kb1 : P.kb0;
            float* vwcur = (t & 1) ? P.vw1 : P.vw0;

            float xiv[2][4];
#pragma unroll
            for (int m = 0; m < 2; ++m)
#pragma unroll
                for (int r = 0; r < 4; ++r) {
                    const int row = m * 16 + lq * 4 + r;
                    xiv[m][r] = (t == 0)
                        ? P.x[(size_t)(m0 + row) * XROW + (TIN - 1) * Fh + f]
                        : dinL[row];
                }
            // ---- LSTM (h from LDS, c in regs) ----
            bf16x8 af[2][8];
#pragma unroll
            for (int m = 0; m < 2; ++m)
#pragma unroll
                for (int k = 0; k < 8; ++k)
                    af[m][k] = *(const bf16x8*)&h2s[m * 16 + lr][k * 32 + lk];
            __syncthreads();
            const ushort* Wb = P.dWhh + (size_t)f * (H4 * H);
#pragma unroll 1
            for (int jt = 0; jt < 4; ++jt) {
                const int j = w * 64 + jt * 16 + lr;
                f32x4 acc[4][2] = {};
#pragma unroll
                for (int g = 0; g < 4; ++g) {
                    const ushort* wp = Wb + (size_t)(g * H + j) * H + lk;
#pragma unroll
                    for (int k = 0; k < 8; ++k) {
                        const bf16x8 b8 = *(const bf16x8*)(wp + k * 32);
                        acc[g][0] = __builtin_amdgcn_mfma_f32_16x16x32_bf16(af[0][k], b8, acc[g][0], 0, 0, 0);
                        acc[g][1] = __builtin_amdgcn_mfma_f32_16x16x32_bf16(af[1][k], b8, acc[g][1], 0, 0, 0);
                    }
                }
#pragma unroll
                for (int m = 0; m < 2; ++m)
#pragma unroll
                    for (int r = 0; r < 4; ++r) {
                        const int row = m * 16 + lq * 4 + r;
                        const float xi = xiv[m][r];
                        const float ig = sigmf(acc[0][m][r] + bsum[jt][0] + xi * wxr[jt][0]);
                        const float fg = sigmf(acc[1][m][r] + bsum[jt][1] + xi * wxr[jt][1]);
                        const float gg = tanhf_(acc[2][m][r] + bsum[jt][2] + xi * wxr[jt][2]);
                        const float og = sigmf(acc[3][m][r] + bsum[jt][3] + xi * wxr[jt][3]);
                        const float cn = fg * cd[m][jt][r] + ig * gg;
                        cd[m][jt][r] = cn;
                        h2s[row][j] = f2bf(og * tanhf_(cn));
                    }
            }
            __syncthreads();
            // ---- fc1 ----
            bf16x8 a2[2][8];
#pragma unroll
            for (int m = 0; m < 2; ++m)
#pragma unroll
                for (int k = 0; k < 8; ++k)
                    a2[m][k] = *(const bf16x8*)&h2s[m * 16 + lr][k * 32 + lk];
            const ushort* Wf = P.f1Wb + (size_t)f * H * H;
#pragma unroll 1
            for (int nt = 0; nt < 4; ++nt) {
                const int n = w * 64 + nt * 16 + lr;
                f32x4 acc0 = {}, acc1 = {};
                const ushort* wp = Wf + (size_t)n * H + lk;
#pragma unroll
                for (int k = 0; k < 8; ++k) {
                    const bf16x8 b8 = *(const bf16x8*)(wp + k * 32);
                    acc0 = __builtin_amdgcn_mfma_f32_16x16x32_bf16(a2[0][k], b8, acc0, 0, 0, 0);
                    acc1 = __builtin_amdgcn_mfma_f32_16x16x32_bf16(a2[1][k], b8, acc1, 0, 0, 0);
                }
                const float bv = P.f1b[f * H + n];
#pragma unroll
                for (int r = 0; r < 4; ++r) {
                    float v0 = acc0[r] + bv; v0 = (v0 > 0.f) ? v0 : 0.01f * v0;
                    as2[lq * 4 + r][n] = f2bf(v0);
                    float v1 = acc1[r] + bv; v1 = (v1 > 0.f) ? v1 : 0.01f * v1;
                    as2[16 + lq * 4 + r][n] = f2bf(v1);
                }
            }
            __syncthreads();
            // ---- q (LDS) / k (global L2) projection ----
            bf16x8 a3[2][8];
#pragma unroll
            for (int m = 0; m < 2; ++m)
#pragma unroll
                for (int k = 0; k < 8; ++k)
                    a3[m][k] = *(const bf16x8*)&as2[m * 16 + lr][k * 32 + lk];
            const ushort* Wi = P.inWb + (size_t)f * 768 * H;
#pragma unroll 1
            for (int nt = 0; nt < 8; ++nt) {
                const int n0 = w * 128 + nt * 16;
                f32x4 acc0 = {}, acc1 = {};
                const ushort* wp = Wi + (size_t)(n0 + lr) * H + lk;
#pragma unroll
                for (int k = 0; k < 8; ++k) {
                    const bf16x8 b8 = *(const bf16x8*)(wp + k * 32);
                    acc0 = __builtin_amdgcn_mfma_f32_16x16x32_bf16(a3[0][k], b8, acc0, 0, 0, 0);
                    acc1 = __builtin_amdgcn_mfma_f32_16x16x32_bf16(a3[1][k], b8, acc1, 0, 0, 0);
                }
                const float bv = P.inb[f * 768 + n0 + lr];
#pragma unroll
                for (int m = 0; m < 2; ++m)
#pragma unroll
                    for (int r = 0; r < 4; ++r) {
                        const float v = (m ? acc1[r] : acc0[r]) + bv;
                        const int row = m * 16 + lq * 4 + r;
                        if (n0 < 256)
                            qs[row][n0 + lr] = f2bf(v * 0.0625f);
                        else
                            kcur[((size_t)f * Bsz + m0 + row) * H + n0 - 256 + lr] = f2bf(v);
                    }
            }
            // ---- vw ----
            {
                const float4 u4 = *(const float4*)(P.u + f * H + l * 4);
#pragma unroll 1
                for (int rr = 0; rr < 8; ++rr) {
                    const int mloc = w * 8 + rr;
                    const ushort4 a4 = *(const ushort4*)&as2[mloc][l * 4];
                    float s = bf2f(a4.x) * u4.x + bf2f(a4.y) * u4.y
                            + bf2f(a4.z) * u4.z + bf2f(a4.w) * u4.w;
#pragma unroll
                    for (int d = 1; d < 64; d <<= 1) s += __shfl_xor(s, d);
                    if (l == 0) vwcur[f * Bsz + m0 + mloc] = s + P.dconst[f];
                }
            }
            // ---- per-f barrier: k/vw complete in XCD L2 ----
            gbar(fcnt, (unsigned)(t + 1) * 32u);
            // ---- attention (2-kf batched loads: one vmcnt stall per 2 kf) ----
            {
                bf16x8 qf[2][8];
#pragma unroll
                for (int m = 0; m < 2; ++m)
#pragma unroll
                    for (int k = 0; k < 8; ++k)
                        qf[m][k] = *(const bf16x8*)&qs[m * 16 + lr][k * 32 + lk];
                float mM0 = -1e30f, lS0 = 0.f, oS0 = 0.f;
                float mM1 = -1e30f, lS1 = 0.f, oS1 = 0.f;
                const int kb0r = w * 256;
#pragma unroll 1
                for (int kf = 0; kf < 16; kf += 2) {
                    const int kbA = kb0r + kf * 16;
                    const ushort* baseA = kcur + ((size_t)f * Bsz + kbA + lr) * H + lk;
                    const ushort* baseB = baseA + 16 * H;
                    const float* pvA = vwcur + f * Bsz + kbA + lq * 4;
                    const float* pvB = pvA + 16;
                    f32x4 A0, A1, A2, A3, A4, A5, A6, A7;
                    f32x4 B0, B1, B2, B3, B4, B5, B6, B7;
                    f32x4 vA, vB;
                    asm volatile(
                        "global_load_dwordx4 %0, %18, off sc0\n\t"
                        "global_load_dwordx4 %1, %18, off offset:64 sc0\n\t"
                        "global_load_dwordx4 %2, %18, off offset:128 sc0\n\t"
                        "global_load_dwordx4 %3, %18, off offset:192 sc0\n\t"
                        "global_load_dwordx4 %4, %18, off offset:256 sc0\n\t"
                        "global_load_dwordx4 %5, %18, off offset:320 sc0\n\t"
                        "global_load_dwordx4 %6, %18, off offset:384 sc0\n\t"
                        "global_load_dwordx4 %7, %18, off offset:448 sc0\n\t"
                        "global_load_dwordx4 %8, %19, off sc0\n\t"
                        "global_load_dwordx4 %9, %19, off offset:64 sc0\n\t"
                        "global_load_dwordx4 %10, %19, off offset:128 sc0\n\t"
                        "global_load_dwordx4 %11, %19, off offset:192 sc0\n\t"
                        "global_load_dwordx4 %12, %19, off offset:256 sc0\n\t"
                        "global_load_dwordx4 %13, %19, off offset:320 sc0\n\t"
                        "global_load_dwordx4 %14, %19, off offset:384 sc0\n\t"
                        "global_load_dwordx4 %15, %19, off offset:448 sc0\n\t"
                        "global_load_dwordx4 %16, %20, off sc0\n\t"
                        "global_load_dwordx4 %17, %21, off sc0\n\t"
                        "s_waitcnt vmcnt(0)"
                        : "=&v"(A0), "=&v"(A1), "=&v"(A2), "=&v"(A3),
                          "=&v"(A4), "=&v"(A5), "=&v"(A6), "=&v"(A7),
                          "=&v"(B0), "=&v"(B1), "=&v"(B2), "=&v"(B3),
                          "=&v"(B4), "=&v"(B5), "=&v"(B6), "=&v"(B7),
                          "=&v"(vA), "=&v"(vB)
                        : "v"(baseA), "v"(baseB), "v"(pvA), "v"(pvB)
                        : "memory");
                    __builtin_amdgcn_sched_barrier(0);
                    // ---- kf A ----
                    {
                        f32x4 acc0 = {}, acc1 = {};
                        const bf16x8 k0 = *(bf16x8*)&A0, k1 = *(bf16x8*)&A1,
                                     k2 = *(bf16x8*)&A2, k3 = *(bf16x8*)&A3,
                                     k4 = *(bf16x8*)&A4, k5 = *(bf16x8*)&A5,
                                     k6 = *(bf16x8*)&A6, k7 = *(bf16x8*)&A7;
                        acc0 = __builtin_amdgcn_mfma_f32_16x16x32_bf16(k0, qf[0][0], acc0, 0, 0, 0);
                        acc1 = __builtin_amdgcn_mfma_f32_16x16x32_bf16(k0, qf[1][0], acc1, 0, 0, 0);
                        acc0 = __builtin_amdgcn_mfma_f32_16x16x32_bf16(k1, qf[0][1], acc0, 0, 0, 0);
                        acc1 = __builtin_amdgcn_mfma_f32_16x16x32_bf16(k1, qf[1][1], acc1, 0, 0, 0);
                        acc0 = __builtin_amdgcn_mfma_f32_16x16x32_bf16(k2, qf[0][2], acc0, 0, 0, 0);
                        acc1 = __builtin_amdgcn_mfma_f32_16x16x32_bf16(k2, qf[1][2], acc1, 0, 0, 0);
                        acc0 = __builtin_amdgcn_mfma_f32_16x16x32_bf16(k3, qf[0][3], acc0, 0, 0, 0);
                        acc1 = __builtin_amdgcn_mfma_f32_16x16x32_bf16(k3, qf[1][3], acc1, 0, 0, 0);
                        acc0 = __builtin_amdgcn_mfma_f32_16x16x32_bf16(k4, qf[0][4], acc0, 0, 0, 0);
                        acc1 = __builtin_amdgcn_mfma_f32_16x16x32_bf16(k4, qf[1][4], acc1, 0, 0, 0);
                        acc0 = __builtin_amdgcn_mfma_f32_16x16x32_bf16(k5, qf[0][5], acc0, 0, 0, 0);
                        acc1 = __builtin_amdgcn_mfma_f32_16x16x32_bf16(k5, qf[1][5], acc1, 0, 0, 0);
                        acc0 = __builtin_amdgcn_mfma_f32_16x16x32_bf16(k6, qf[0][6], acc0, 0, 0, 0);
                        acc1 = __builtin_amdgcn_mfma_f32_16x16x32_bf16(k6, qf[1][6], acc1, 0, 0, 0);
                        acc0 = __builtin_amdgcn_mfma_f32_16x16x32_bf16(k7, qf[0][7], acc0, 0, 0, 0);
                        acc1 = __builtin_amdgcn_mfma_f32_16x16x32_bf16(k7, qf[1][7], acc1, 0, 0, 0);
                        {
                            const float mx = fmaxf(fmaxf(acc0[0], acc0[1]), fmaxf(acc0[2], acc0[3]));
                            const float mn = fmaxf(mM0, mx);
                            const float sc = __expf(mM0 - mn);
                            const float e0 = __expf(acc0[0] - mn), e1 = __expf(acc0[1] - mn);
                            const float e2 = __expf(acc0[2] - mn), e3 = __expf(acc0[3] - mn);
                            lS0 = lS0 * sc + (e0 + e1 + e2 + e3);
                            oS0 = oS0 * sc + (e0 * vA[0] + e1 * vA[1] + e2 * vA[2] + e3 * vA[3]);
                            mM0 = mn;
                        }
                        {
                            const float mx = fmaxf(fmaxf(acc1[0], acc1[1]), fmaxf(acc1[2], acc1[3]));
                            const float mn = fmaxf(mM1, mx);
                            const float sc = __expf(mM1 - mn);
                            const float e0 = __expf(acc1[0] - mn), e1 = __expf(acc1[1] - mn);
                            const float e2 = __expf(acc1[2] - mn), e3 = __expf(acc1[3] - mn);
                            lS1 = lS1 * sc + (e0 + e1 + e2 + e3);
                            oS1 = oS1 * sc + (e0 * vA[0] + e1 * vA[1] + e2 * vA[2] + e3 * vA[3]);
                            mM1 = mn;
                        }
                    }
                    // ---- kf B ----
                    {
                        f32x4 acc0 = {}, acc1 = {};
                        const bf16x8 k0 = *(bf16x8*)&B0, k1 = *(bf16x8*)&B1,
                                     k2 = *(bf16x8*)&B2, k3 = *(bf16x8*)&B3,
                                     k4 = *(bf16x8*)&B4, k5 = *(bf16x8*)&B5,
                                     k6 = *(bf16x8*)&B6, k7 = *(bf16x8*)&B7;
                        acc0 = __builtin_amdgcn_mfma_f32_16x16x32_bf16(k0, qf[0][0], acc0, 0, 0, 0);
                        acc1 = __builtin_amdgcn_mfma_f32_16x16x32_bf16(k0, qf[1][0], acc1, 0, 0, 0);
                        acc0 = __builtin_amdgcn_mfma_f32_16x16x32_bf16(k1, qf[0][1], acc0, 0, 0, 0);
                        acc1 = __builtin_amdgcn_mfma_f32_16x16x32_bf16(k1, qf[1][1], acc1, 0, 0, 0);
                        acc0 = __builtin_amdgcn_mfma_f32_16x16x32_bf16(k2, qf[0][2], acc0, 0, 0, 0);
                        acc1 = __builtin_amdgcn_mfma_f32_16x16x32_bf16(k2, qf[1][2], acc1, 0, 0, 0);
                        acc0 = __builtin_amdgcn_mfma_f32_16x16x32_bf16(k3, qf[0][3], acc0, 0, 0, 0);
                        acc1 = __builtin_amdgcn_mfma_f32_16x16x32_bf16(k3, qf[1][3], acc1, 0, 0, 0);
                        acc0 = __builtin_amdgcn_mfma_f32_16x16x32_bf16(k4, qf[0][4], acc0, 0, 0, 0);
                        acc1 = __builtin_amdgcn_mfma_f32_16x16x32_bf16(k4, qf[1][4], acc1, 0, 0, 0);
                        acc0 = __builtin_amdgcn_mfma_f32_16x16x32_bf16(k5, qf[0][5], acc0, 0, 0, 0);
                        acc1 = __builtin_amdgcn_mfma_f32_16x16x32_bf16(k5, qf[1][5], acc1, 0, 0, 0);
                        acc0 = __builtin_amdgcn_mfma_f32_16x16x32_bf16(k6, qf[0][6], acc0, 0, 0, 0);
                        acc1 = __builtin_amdgcn_mfma_f32_16x16x32_bf16(k6, qf[1][6], acc1, 0, 0, 0);
                        acc0 = __builtin_amdgcn_mfma_f32_16x16x32_bf16(k7, qf[0][7], acc0, 0, 0, 0);
                        acc1 = __builtin_amdgcn_mfma_f32_16x16x32_bf16(k7, qf[1][7], acc1, 0, 0, 0);
                        {
                            const float mx = fmaxf(fmaxf(acc0[0], acc0[1]), fmaxf(acc0[2], acc0[3]));
                            const float mn = fmaxf(mM0, mx);
                            const float sc = __expf(mM0 - mn);
                            const float e0 = __expf(acc0[0] - mn), e1 = __expf(acc0[1] - mn);
                            const float e2 = __expf(acc0[2] - mn), e3 = __expf(acc0[3] - mn);
                            lS0 = lS0 * sc + (e0 + e1 + e2 + e3);
                            oS0 = oS0 * sc + (e0 * vB[0] + e1 * vB[1] + e2 * vB[2] + e3 * vB[3]);
                            mM0 = mn;
                        }
                        {
                            const float mx = fmaxf(fmaxf(acc1[0], acc1[1]), fmaxf(acc1[2], acc1[3]));
                            const float mn = fmaxf(mM1, mx);
                            const float sc = __expf(mM1 - mn);
                            const float e0 = __expf(acc1[0] - mn), e1 = __expf(acc1[1] - mn);
                            const float e2 = __expf(acc1[2] - mn), e3 = __expf(acc1[3] - mn);
                            lS1 = lS1 * sc + (e0 + e1 + e2 + e3);
                            oS1 = oS1 * sc + (e0 * vB[0] + e1 * vB[1] + e2 * vB[2] + e3 * vB[3]);
                            mM1 = mn;
                        }
                    }
                }
#pragma unroll
                for (int d = 16; d < 64; d <<= 1) {
                    {
                        const float m2 = __shfl_xor(mM0, d), l2 = __shfl_xor(lS0, d), o2 = __shfl_xor(oS0, d);
                        const float mn = fmaxf(mM0, m2);
                        const float sa = __expf(mM0 - mn), sb = __expf(m2 - mn);
                        lS0 = lS0 * sa + l2 * sb; oS0 = oS0 * sa + o2 * sb; mM0 = mn;
                    }
                    {
                        const float m2 = __shfl_xor(mM1, d), l2 = __shfl_xor(lS1, d), o2 = __shfl_xor(oS1, d);
                        const float mn = fmaxf(mM1, m2);
                        const float sa = __expf(mM1 - mn), sb = __expf(m2 - mn);
                        lS1 = lS1 * sa + l2 * sb; oS1 = oS1 * sa + o2 * sb; mM1 = mn;
                    }
                }
                if (l < 16) {
                    tri[w][0][l][0] = mM0; tri[w][0][l][1] = lS0; tri[w][0][l][2] = oS0;
                    tri[w][1][l][0] = mM1; tri[w][1][l][1] = lS1; tri[w][1][l][2] = oS1;
                }
                __syncthreads();
                if (tid < 32) {
                    const int m = tid >> 4, qr = tid & 15;
                    float M = tri[0][m][qr][0], L = tri[0][m][qr][1], O = tri[0][m][qr][2];
#pragma unroll
                    for (int ww = 1; ww < 4; ++ww) {
                        const float m2 = tri[ww][m][qr][0], l2 = tri[ww][m][qr][1], o2 = tri[ww][m][qr][2];
                        const float mn = fmaxf(M, m2);
                        const float sa = __expf(M - mn), sb = __expf(m2 - mn);
                        L = L * sa + l2 * sb; O = O * sa + o2 * sb; M = mn;
                    }
                    float val = __fdividef(O, L) + P.ccv[f];
                    val = (val > 0.f) ? val : 0.01f * val;
                    const int b = m0 + m * 16 + qr;
                    P.out[(size_t)b * (TOUT * Fh) + (size_t)t * Fh + f] = val;
                    dinL[m * 16 + qr] = val;
                }
                __syncthreads();
            }
        }
    }
}

extern "C" void kernel_launch(void* const* d_in, const int* in_sizes, int n_in,
                              void* d_out, int out_size, void* d_ws, size_t ws_size,
                              hipStream_t stream)
{
    const float* x     = (const float*)d_in[0];
    const float* eWih0 = (const float*)d_in[1];
    const float* eWhh0 = (const float*)d_in[2];
    const float* ebih0 = (const float*)d_in[3];
    const float* ebhh0 = (const float*)d_in[4];
    const float* eWih1 = (const float*)d_in[5];
    const float* eWhh1 = (const float*)d_in[6];
    const float* ebih1 = (const float*)d_in[7];
    const float* ebhh1 = (const float*)d_in[8];
    const float* dWih  = (const float*)d_in[9];
    const float* dWhh  = (const float*)d_in[10];
    const float* dbih  = (const float*)d_in[11];
    const float* dbhh  = (const float*)d_in[12];
    const float* f1W   = (const float*)d_in[13];
    const float* f1b   = (const float*)d_in[14];
    const float* inW   = (const float*)d_in[15];
    const float* inb   = (const float*)d_in[16];
    const float* oW    = (const float*)d_in[17];
    const float* ob    = (const float*)d_in[18];
    const float* f2W   = (const float*)d_in[19];
    const float* f2b   = (const float*)d_in[20];

    char* base = (char*)d_ws;
    size_t o = 0;
    auto alloc = [&](size_t bytes) { void* p = base + o; o += (bytes + 255) & ~(size_t)255; return p; };
    ushort* h0A = (ushort*)alloc(BH * 2);   // swizzled [8][B][32]
    ushort* h1A = (ushort*)alloc(BH * 2);
    ushort* h0B = (ushort*)alloc(BH * 2);
    ushort* h1B = (ushort*)alloc(BH * 2);
    ushort* hm  = (ushort*)alloc(BH * 2);
    float*  cm  = (float*)alloc(BH * 4);
    ushort* kb0 = (ushort*)alloc(8 * BH * 2);
    ushort* kb1 = (ushort*)alloc(8 * BH * 2);
    float*  vw0 = (float*)alloc((size_t)Fh * Bsz * 4);
    float*  vw1 = (float*)alloc((size_t)Fh * Bsz * 4);
    float*  ubuf = (float*)alloc((size_t)Fh * H * 4);
    float*  dbuf = (float*)alloc(Fh * 4);
    float*  ccb  = (float*)alloc(Fh * 4);
    unsigned* bar = (unsigned*)alloc(3072 * 4);
    ushort* wWhh0 = (ushort*)alloc((size_t)H4 * H * 2);
    ushort* wWih0p= (ushort*)alloc((size_t)H4 * 32 * 2);
    ushort* wWih1 = (ushort*)alloc((size_t)H4 * H * 2);
    ushort* wWhh1 = (ushort*)alloc((size_t)H4 * H * 2);
    ushort* wdWhh = (ushort*)alloc((size_t)8 * H4 * H * 2);
    ushort* wf1W  = (ushort*)alloc((size_t)8 * H * H * 2);
    ushort* winW  = (ushort*)alloc((size_t)8 * 768 * H * 2);

    const dim3 blk(256);

    // zero all four h ping-pong buffers (skew reads them as step "-1") + bar
    hipMemsetAsync(d_ws, 0, BH * 2 * 4, stream);
    hipMemsetAsync(bar, 0, 3072 * 4, stream);

    cast_f32_bf16<<<dim3(512), blk, 0, stream>>>(eWhh0, wWhh0, H4 * H);
    cast_f32_bf16<<<dim3(512), blk, 0, stream>>>(eWih1, wWih1, H4 * H);
    cast_f32_bf16<<<dim3(512), blk, 0, stream>>>(eWhh1, wWhh1, H4 * H);
    cast_pad_wih0<<<dim3(128), blk, 0, stream>>>(eWih0, wWih0p);
    cast_f32_bf16<<<dim3(1024), blk, 0, stream>>>(dWhh, wdWhh, 8 * H4 * H);
    cast_f32_bf16<<<dim3(512), blk, 0, stream>>>(f1W, wf1W, 8 * H * H);
    cast_f32_bf16<<<dim3(1024), blk, 0, stream>>>(inW, winW, 8 * 768 * H);
    precompute_kernel<<<dim3(8), blk, 0, stream>>>(oW, ob, f2W, f2b, inW, inb,
                                                   ubuf, dbuf, ccb);

    MP P;
    P.x = x; P.ebih0 = ebih0; P.ebhh0 = ebhh0; P.ebih1 = ebih1; P.ebhh1 = ebhh1;
    P.Whh0 = wWhh0; P.Wih0p = wWih0p; P.Wih1 = wWih1; P.Whh1 = wWhh1;
    P.h0A = h0A; P.h0B = h0B; P.h1A = h1A; P.h1B = h1B;
    P.hm = hm; P.cm = cm;
    P.dWhh = wdWhh; P.f1Wb = wf1W; P.inWb = winW;
    P.dWih = dWih; P.dbih = dbih; P.dbhh = dbhh; P.f1b = f1b; P.inb = inb;
    P.u = ubuf; P.dconst = dbuf; P.ccv = ccb;
    P.kb0 = kb0; P.kb1 = kb1; P.vw0 = vw0; P.vw1 = vw1;
    P.out = (float*)d_out; P.bar = bar;

    mega7<<<dim3(256), blk, 0, stream>>>(P);

    (void)in_sizes; (void)n_in; (void)out_size; (void)ws_size;
}